// Round 6
// baseline (2689.880 us; speedup 1.0000x reference)
//
#include <hip/hip_runtime.h>
#include <hip/hip_bf16.h>

// Problem constants
#define B_SZ   2
#define L_SEQ  2048
#define HIDD   2048
#define NH     16
#define QL     1536
#define KVLR   512
#define ROPE_D 64
#define NOPE_D 128
#define VD     128
#define QKD    192   // NOPE + ROPE

typedef __attribute__((ext_vector_type(8))) __bf16 bf16x8;
typedef __attribute__((ext_vector_type(4))) float  f32x4;
typedef __attribute__((ext_vector_type(8))) unsigned short u16x8;

#if __has_builtin(__builtin_amdgcn_exp2f)
#define EXP2(x) __builtin_amdgcn_exp2f(x)
#else
#define EXP2(x) exp2f(x)
#endif

__device__ __forceinline__ float bf2f(unsigned short u) {
    union { float f; unsigned int i; } x; x.i = ((unsigned int)u) << 16; return x.f;
}
__device__ __forceinline__ unsigned short f2bf(float f) {
    __hip_bfloat16 h = __float2bfloat16(f);
    return *reinterpret_cast<unsigned short*>(&h);
}
__device__ __forceinline__ float finclamp(float v) {
    return fminf(fmaxf(v, -3.3e38f), 3.3e38f);
}

// async global->LDS, 16B per lane; LDS dest = wave-uniform base + lane*16.
__device__ __forceinline__ void gld_lds16(const __hip_bfloat16* g, __hip_bfloat16* l)
{
    __builtin_amdgcn_global_load_lds(
        (const __attribute__((address_space(1))) unsigned int*)(g),
        (__attribute__((address_space(3))) unsigned int*)(l),
        16, 0, 0);
}

// ---------------------------------------------------------------------------
__global__ void detect_fp32(const unsigned short* __restrict__ x, int* __restrict__ flag)
{
    if (threadIdx.x == 0 && blockIdx.x == 0) {
        int c = 0;
        for (int i = 0; i < 128; i++) {
            unsigned e = (x[2 * i] >> 7) & 0xFF;
            if (e > 150 || (e > 0 && e < 100)) c++;
        }
        *flag = (c >= 16) ? 1 : 0;
    }
}

// ---------------------------------------------------------------------------
struct ConvDesc {
    const void* src[9];
    __hip_bfloat16* dst[9];
    long long n8[9];
};

__global__ __launch_bounds__(256)
void conv_all(ConvDesc d, const int* __restrict__ flag)
{
    const int seg = blockIdx.y;
    const void* src = d.src[seg];
    __hip_bfloat16* dst = d.dst[seg];
    const long long n8 = d.n8[seg];
    const int isf = *flag;
    long long stride = (long long)gridDim.x * 256;
    for (long long i = (long long)blockIdx.x * 256 + threadIdx.x; i < n8; i += stride) {
        u16x8 o;
        if (isf) {
            const float* s = (const float*)src + i * 8;
            float4 a = *(const float4*)s;
            float4 b = *(const float4*)(s + 4);
            o[0] = f2bf(a.x); o[1] = f2bf(a.y); o[2] = f2bf(a.z); o[3] = f2bf(a.w);
            o[4] = f2bf(b.x); o[5] = f2bf(b.y); o[6] = f2bf(b.z); o[7] = f2bf(b.w);
        } else {
            o = ((const u16x8*)src)[i];
        }
        ((u16x8*)dst)[i] = o;
    }
}

// ---------------------------------------------------------------------------
// C = scale*(A.B^T), bf16, 128x128 tile, BK=32, global_load_lds staging.
// ropeMode: traditional RoPE on cols with (col%192)>=128 in the epilogue.
// ---------------------------------------------------------------------------
__global__ __launch_bounds__(256)
void gemm_bt(const __hip_bfloat16* __restrict__ A,
             const __hip_bfloat16* __restrict__ Bm,
             void* __restrict__ Cv,
             int M, int N, int K, int lda, int ldb, int ldc,
             float scale,
             int dA, int mA, long long sA,
             int dB, int mB, long long sB, long long sC,
             const int* __restrict__ flagp, int fp32out, int ropeMode)
{
    int z = blockIdx.z;
    A  += (long long)((z / dA) % mA) * sA;
    Bm += (long long)((z / dB) % mB) * sB;
    const long long coff = (long long)z * sC;

    __shared__ __hip_bfloat16 As[128 * 32];
    __shared__ __hip_bfloat16 Bs[128 * 32];

    const int tid  = threadIdx.x;
    const int lane = tid & 63;
    const int wid  = tid >> 6;
    const int quad = lane >> 4;
    const int l15  = lane & 15;
    const int wm   = (wid >> 1) * 64;
    const int wn   = (wid & 1) * 64;

    const int m0 = blockIdx.y * 128;
    const int n0 = blockIdx.x * 128;

    const int srow = lane >> 2;
    const int scol = (lane & 3) * 8;

    f32x4 acc[4][4] = {};

    for (int k0 = 0; k0 < K; k0 += 32) {
        __syncthreads();
        for (int i = 0; i < 2; i++) {
            int rbase = wid * 32 + i * 16;
            int r = rbase + srow;
            gld_lds16(A + (long long)(m0 + r) * lda + k0 + scol, &As[rbase * 32]);
            int gn = n0 + r; if (gn >= N) gn = N - 1;
            gld_lds16(Bm + (long long)gn * ldb + k0 + scol, &Bs[rbase * 32]);
        }
        __syncthreads();

        bf16x8 af[4], bfv[4];
        for (int mt = 0; mt < 4; mt++)
            af[mt] = *reinterpret_cast<const bf16x8*>(
                &As[(wm + mt * 16 + l15) * 32 + quad * 8]);
        for (int nt = 0; nt < 4; nt++)
            bfv[nt] = *reinterpret_cast<const bf16x8*>(
                &Bs[(wn + nt * 16 + l15) * 32 + quad * 8]);
        for (int mt = 0; mt < 4; mt++)
            for (int nt = 0; nt < 4; nt++)
                acc[mt][nt] = __builtin_amdgcn_mfma_f32_16x16x32_bf16(
                    af[mt], bfv[nt], acc[mt][nt], 0, 0, 0);
    }

    const int f32o = fp32out && (*flagp);

    // Epilogue: C/D layout col=lane&15, row=quad*4+reg
    for (int mt = 0; mt < 4; mt++) {
        int row = m0 + wm + mt * 16 + quad * 4;
        for (int nt = 0; nt < 4; nt++) {
            int col = n0 + wn + nt * 16 + l15;
            int colm = col % 192;
            bool doRope = ropeMode && (colm >= 128);   // wave-uniform per tile
            if (col < N) {
                for (int r = 0; r < 4; r++) {
                    float val = acc[mt][nt][r] * scale;
                    if (doRope) {
                        int l = (row + r) & (L_SEQ - 1);
                        int i = (colm - 128) >> 1;
                        float freq = exp2f(-(float)i * (13.287712379549449f / 32.0f));
                        float th = (float)l * freq;
                        float s = __sinf(th), c = __cosf(th);
                        float pa = __shfl_xor(val, 1);
                        val = (l15 & 1) ? (pa * s + val * c) : (val * c - pa * s);
                    }
                    long long idx = coff + (long long)(row + r) * ldc + col;
                    if (f32o) ((float*)Cv)[idx] = finclamp(val);
                    else      ((__hip_bfloat16*)Cv)[idx] = __float2bfloat16(finclamp(val));
                }
            } else if (doRope) {
                for (int r = 0; r < 4; r++) (void)__shfl_xor(acc[mt][nt][r], 1);
            }
        }
    }
}

// ---------------------------------------------------------------------------
__global__ __launch_bounds__(256)
void rmsnorm_qa(__hip_bfloat16* __restrict__ X, const __hip_bfloat16* __restrict__ W,
                int ldx)
{
    int row = blockIdx.x;
    __hip_bfloat16* xr = X + (long long)row * ldx;
    int tid = threadIdx.x;
    bool act = tid < (QL / 8);
    float v[8];
    float ss = 0.f;
    if (act) {
        u16x8 raw = *reinterpret_cast<const u16x8*>(xr + tid * 8);
        for (int j = 0; j < 8; j++) {
            v[j] = bf2f(((const unsigned short*)&raw)[j]);
            ss += v[j] * v[j];
        }
    }
    for (int m = 1; m < 64; m <<= 1) ss += __shfl_xor(ss, m, 64);
    __shared__ float ws4[4];
    if ((tid & 63) == 0) ws4[tid >> 6] = ss;
    __syncthreads();
    float tot = ws4[0] + ws4[1] + ws4[2] + ws4[3];
    float inv = rsqrtf(tot / (float)QL + 1e-5f);
    if (act) {
        u16x8 wr = *reinterpret_cast<const u16x8*>(W + tid * 8);
        u16x8 o;
        for (int j = 0; j < 8; j++)
            ((unsigned short*)&o)[j] =
                f2bf(finclamp(v[j] * inv * bf2f(((const unsigned short*)&wr)[j])));
        *reinterpret_cast<u16x8*>(xr + tid * 8) = o;
    }
}

// ---------------------------------------------------------------------------
__global__ __launch_bounds__(256)
void kv_norm_rope(const __hip_bfloat16* __restrict__ CQ,
                  const __hip_bfloat16* __restrict__ W,
                  __hip_bfloat16* __restrict__ KVLAT,
                  __hip_bfloat16* __restrict__ KPE)
{
    int row = blockIdx.x * 4 + (threadIdx.x >> 6);
    int l = row & (L_SEQ - 1);
    int t = threadIdx.x & 63;
    const __hip_bfloat16* cr = CQ + (long long)row * 2112;

    float v[8]; float ss = 0.f;
    u16x8 raw = *reinterpret_cast<const u16x8*>(cr + t * 8);
    for (int j = 0; j < 8; j++) {
        v[j] = bf2f(((const unsigned short*)&raw)[j]);
        ss += v[j] * v[j];
    }
    for (int m = 1; m < 64; m <<= 1) ss += __shfl_xor(ss, m, 64);
    float inv = rsqrtf(ss / (float)KVLR + 1e-5f) * 2.0f;  // SKV = 2
    u16x8 wr = *reinterpret_cast<const u16x8*>(W + t * 8);
    u16x8 o;
    for (int j = 0; j < 8; j++)
        ((unsigned short*)&o)[j] =
            f2bf(finclamp(v[j] * inv * bf2f(((const unsigned short*)&wr)[j])));
    *reinterpret_cast<u16x8*>(KVLAT + (long long)row * KVLR + t * 8) = o;

    if (t < 32) {
        float freq = exp2f(-(float)t * (13.287712379549449f / 32.0f));
        float th = (float)l * freq;
        float s = __sinf(th), c = __cosf(th);
        float x1 = __bfloat162float(cr[512 + 2 * t]);
        float x2 = __bfloat162float(cr[512 + 2 * t + 1]);
        __hip_bfloat16* kp = KPE + (long long)row * 64;
        kp[2 * t]     = __float2bfloat16(finclamp(x1 * c - x2 * s));
        kp[2 * t + 1] = __float2bfloat16(finclamp(x1 * s + x2 * c));
    }
}

// ---------------------------------------------------------------------------
__global__ __launch_bounds__(256)
void transpose_embed(const __hip_bfloat16* __restrict__ WE,
                     __hip_bfloat16* __restrict__ WB)
{
    int h = blockIdx.y;
    int k0 = blockIdx.x * 64;
    __shared__ __hip_bfloat16 t[64][136];
    int tid = threadIdx.x;
    for (int it = 0; it < 4; it++) {
        int s = tid + it * 256;
        int k = s >> 4, cg = (s & 15) * 8;
        u16x8 v = *reinterpret_cast<const u16x8*>(
            WE + ((long long)h * KVLR + k0 + k) * NOPE_D + cg);
        *reinterpret_cast<u16x8*>(&t[k][cg]) = v;
    }
    __syncthreads();
    for (int it = 0; it < 4; it++) {
        int s = tid + it * 256;
        int n = s >> 3, kg = (s & 7) * 8;
        u16x8 o;
        for (int j = 0; j < 8; j++)
            ((unsigned short*)&o)[j] = *reinterpret_cast<unsigned short*>(&t[kg + j][n]);
        *reinterpret_cast<u16x8*>(WB + ((long long)h * 128 + n) * KVLR + k0 + kg) = o;
    }
}

// ---------------------------------------------------------------------------
// Split-K flash attention, static-max (partials exactly additive).
// Q (B*L,H*192) pre-scaled by SQ*SCALE*log2e, roped. Kb (B*H,L,128);
// Vt (B*H,128,L); KPE (B,L,64).  Grid: x = 48 chunk-units, y = 32 bh.
// Chunk0 = key tiles [0,min(qt+1,16)), chunk1 = [16,qt+1) (qt>=16 only).
// Outputs unnormalized fp32 O + l per chunk; combine_o merges.
// ---------------------------------------------------------------------------
__global__ __launch_bounds__(256)
void flash_attn(const __hip_bfloat16* __restrict__ Q,
                const __hip_bfloat16* __restrict__ Kb,
                const __hip_bfloat16* __restrict__ Vt,
                const __hip_bfloat16* __restrict__ KPE,
                float* __restrict__ O0, float* __restrict__ O1,
                float* __restrict__ L0, float* __restrict__ L1)
{
    // map u -> (qt, chunk): big blocks (16 tiles) first
    const int u = blockIdx.x;
    int qt, ch;
    if (u < 32) { int k = u >> 1; qt = 31 - k; ch = u & 1; }
    else        { qt = 47 - u;    ch = 0; }
    const int q0 = qt * 64;
    const int t0 = ch ? 16 : 0;
    const int t1 = ch ? (qt + 1) : ((qt + 1 < 16) ? (qt + 1) : 16);

    const int bh = blockIdx.y;
    const int b = bh >> 4;
    const int h = bh & 15;

    __shared__ __hip_bfloat16 Ks[64 * 200];
    __shared__ __hip_bfloat16 Vs[128 * 72];
    __shared__ __hip_bfloat16 Ps[4][16 * 72];

    const int tid  = threadIdx.x;
    const int lane = tid & 63;
    const int w    = tid >> 6;
    const int quad = lane >> 4;
    const int l15  = lane & 15;

    const __hip_bfloat16* Kbh  = Kb + (long long)bh * L_SEQ * 128;
    const __hip_bfloat16* Vth  = Vt + (long long)bh * 128 * L_SEQ;
    const __hip_bfloat16* KPEb = KPE + (long long)b * L_SEQ * 64;

    bf16x8 qf[6];
    {
        long long qoff = (long long)(b * L_SEQ + q0 + w * 16 + l15) * (NH * QKD) + h * QKD;
        for (int kk = 0; kk < 6; kk++)
            qf[kk] = *reinterpret_cast<const bf16x8*>(Q + qoff + kk * 32 + quad * 8);
    }

    f32x4 o_acc[8] = {};
    float l_run[4] = {0.f, 0.f, 0.f, 0.f};

    for (int kt = t0; kt < t1; kt++) {
        const int kk0 = kt * 64;
        const bool partial = (kt == qt);     // diagonal tile only
        __syncthreads();
        for (int it = 0; it < 6; it++) {
            int s = tid + it * 256;
            int r = s / 24, cg = s % 24;
            u16x8 v;
            if (cg < 16)
                v = *reinterpret_cast<const u16x8*>(
                    Kbh + (long long)(kk0 + r) * 128 + cg * 8);
            else
                v = *reinterpret_cast<const u16x8*>(
                    KPEb + (long long)(kk0 + r) * 64 + (cg - 16) * 8);
            *reinterpret_cast<u16x8*>(&Ks[r * 200 + cg * 8]) = v;
        }
        for (int it = 0; it < 4; it++) {
            int s = tid + it * 256;
            int vd = s >> 3, kg = (s & 7) * 8;
            u16x8 v = *reinterpret_cast<const u16x8*>(
                Vth + (long long)vd * L_SEQ + kk0 + kg);
            *reinterpret_cast<u16x8*>(&Vs[vd * 72 + kg]) = v;
        }
        __syncthreads();

        // S' = (Q*log2e) . K^T
        f32x4 sfr[4];
        for (int nt = 0; nt < 4; nt++) {
            f32x4 sacc = {};
            for (int kk = 0; kk < 6; kk++) {
                bf16x8 kf = *reinterpret_cast<const bf16x8*>(
                    &Ks[(nt * 16 + l15) * 200 + kk * 32 + quad * 8]);
                sacc = __builtin_amdgcn_mfma_f32_16x16x32_bf16(qf[kk], kf, sacc, 0, 0, 0);
            }
            sfr[nt] = sacc;
        }

        // p = 2^(S'); causal mask only on the diagonal tile
        const int qrow_base = q0 + w * 16 + quad * 4;
        float rs[4] = {0.f, 0.f, 0.f, 0.f};
        if (partial) {
            for (int nt = 0; nt < 4; nt++) {
                int key = kk0 + nt * 16 + l15;
                for (int r = 0; r < 4; r++) {
                    float p = (key > qrow_base + r) ? 0.f : EXP2(sfr[nt][r]);
                    sfr[nt][r] = p;
                    rs[r] += p;
                }
            }
        } else {
            for (int nt = 0; nt < 4; nt++)
                for (int r = 0; r < 4; r++) {
                    float p = EXP2(sfr[nt][r]);
                    sfr[nt][r] = p;
                    rs[r] += p;
                }
        }

        // P -> LDS first (write latency overlaps the shuffle-reduce below)
        for (int nt = 0; nt < 4; nt++)
            for (int r = 0; r < 4; r++)
                Ps[w][(quad * 4 + r) * 72 + nt * 16 + l15] =
                    __float2bfloat16(sfr[nt][r]);

        for (int r = 0; r < 4; r++) {
            float t = rs[r];
            for (int m = 1; m < 16; m <<= 1) t += __shfl_xor(t, m, 16);
            l_run[r] += t;
        }

        // O += P . V
        for (int ks = 0; ks < 2; ks++) {
            bf16x8 pf = *reinterpret_cast<const bf16x8*>(
                &Ps[w][l15 * 72 + ks * 32 + quad * 8]);
            for (int vt = 0; vt < 8; vt++) {
                bf16x8 vf = *reinterpret_cast<const bf16x8*>(
                    &Vs[(vt * 16 + l15) * 72 + ks * 32 + quad * 8]);
                o_acc[vt] = __builtin_amdgcn_mfma_f32_16x16x32_bf16(pf, vf, o_acc[vt], 0, 0, 0);
            }
        }
    }

    // epilogue: unnormalized fp32 partials
    const int orow = q0 + w * 16 + quad * 4;
    float* Op; float* Lp; long long rbase;
    if (ch == 0) { Op = O0; Lp = L0; rbase = (long long)b * 2048 + orow; }
    else         { Op = O1; Lp = L1; rbase = (long long)b * 1024 + (orow - 1024); }
    for (int r = 0; r < 4; r++) {
        float* op = Op + (rbase + r) * 2048 + h * 128;
        for (int vt = 0; vt < 8; vt++)
            op[vt * 16 + l15] = o_acc[vt][r];
        if (l15 == 0) Lp[(rbase + r) * 16 + h] = l_run[r];
    }
}

// ---------------------------------------------------------------------------
// Combine: aout = (O0 [+ O1]) / (l0 [+ l1]), bf16. grid = 4096 rows.
// Rows with (row%2048) >= 1024 have a chunk1 contribution.
// ---------------------------------------------------------------------------
__global__ __launch_bounds__(256)
void combine_o(const float* __restrict__ O0, const float* __restrict__ O1,
               const float* __restrict__ L0, const float* __restrict__ L1,
               __hip_bfloat16* __restrict__ aout)
{
    const int row = blockIdx.x;
    const int rl = row & 2047;
    const int b = row >> 11;
    const bool has1 = rl >= 1024;
    const long long rowc = (long long)b * 1024 + (rl - 1024);
    const float* o0 = O0 + (long long)row * 2048;
    const float* o1 = O1 + rowc * 2048;
    const int tid = threadIdx.x;
    const int c0 = tid * 8;
    const int h = c0 >> 7;
    float l = L0[(long long)row * 16 + h] + (has1 ? L1[rowc * 16 + h] : 0.f);
    float inv = 1.0f / fmaxf(l, 1e-30f);
    float4 a = *(const float4*)(o0 + c0);
    float4 bb = *(const float4*)(o0 + c0 + 4);
    if (has1) {
        float4 c = *(const float4*)(o1 + c0);
        float4 d = *(const float4*)(o1 + c0 + 4);
        a.x += c.x; a.y += c.y; a.z += c.z; a.w += c.w;
        bb.x += d.x; bb.y += d.y; bb.z += d.z; bb.w += d.w;
    }
    u16x8 o;
    o[0] = f2bf(finclamp(a.x * inv));  o[1] = f2bf(finclamp(a.y * inv));
    o[2] = f2bf(finclamp(a.z * inv));  o[3] = f2bf(finclamp(a.w * inv));
    o[4] = f2bf(finclamp(bb.x * inv)); o[5] = f2bf(finclamp(bb.y * inv));
    o[6] = f2bf(finclamp(bb.z * inv)); o[7] = f2bf(finclamp(bb.w * inv));
    *reinterpret_cast<u16x8*>(aout + (long long)row * 2048 + c0) = o;
}

// ---------------------------------------------------------------------------
extern "C" void kernel_launch(void* const* d_in, const int* in_sizes, int n_in,
                              void* d_out, int out_size, void* d_ws, size_t ws_size,
                              hipStream_t stream)
{
    const long long want[9] = {
        8388608, 3145728, 1536, 4718592, 1179648, 512, 1048576, 1048576, 4194304
    };
    const void* P[9] = {};
    {
        int j = 0;
        for (int i = 0; i < n_in && j < 9; i++)
            if ((long long)in_sizes[i] == want[j]) P[j++] = d_in[i];
        if (!P[8]) {
            const int map[9] = {0, 2, 3, 4, 5, 6, 7, 8, 9};
            for (int j2 = 0; j2 < 9; j2++) P[j2] = d_in[map[j2]];
        }
    }
    (void)ws_size; (void)out_size;

    char* ws = (char*)d_ws;
    int* flag = (int*)ws;
    char* A = ws + 256;

    // Region A: dead after step 7 (q_b GEMM); overlaid by fp32 partials for flash
    __hip_bfloat16* xc     = (__hip_bfloat16*)(A);              // 16,777,216
    __hip_bfloat16* wfused = (__hip_bfloat16*)(A + 16777216);   //  8,650,752
    __hip_bfloat16* wqbc   = (__hip_bfloat16*)(A + 25427968);   //  9,437,184
    __hip_bfloat16* cq     = (__hip_bfloat16*)(A + 34865152);   // 17,301,504 -> A ends 52,166,656
    float* O0 = (float*)(A);                                    // 33,554,432
    float* O1 = (float*)(A + 33554432);                         // 16,777,216
    float* L0 = (float*)(A + 50331648);                         //    262,144
    float* L1 = (float*)(A + 50593792);                         //    131,072  (< 52,166,656 OK)

    long long off = 256 + 52166656;
    auto alloc = [&](long long bytes) {
        char* p = ws + off;
        off += ((bytes + 255) / 256) * 256;
        return p;
    };
    __hip_bfloat16* qlnwc  = (__hip_bfloat16*)alloc(3072);
    __hip_bfloat16* kvlnwc = (__hip_bfloat16*)alloc(1024);
    __hip_bfloat16* wembc  = (__hip_bfloat16*)alloc(2097152);
    __hip_bfloat16* wunec  = (__hip_bfloat16*)alloc(2097152);
    __hip_bfloat16* woc    = (__hip_bfloat16*)alloc(8388608);
    __hip_bfloat16* kvl    = (__hip_bfloat16*)alloc(4194304);
    __hip_bfloat16* kpe    = (__hip_bfloat16*)alloc(524288);
    __hip_bfloat16* wBk    = (__hip_bfloat16*)alloc(2097152);
    __hip_bfloat16* kvK    = (__hip_bfloat16*)alloc(16777216);
    __hip_bfloat16* kvVt   = (__hip_bfloat16*)alloc(16777216);
    __hip_bfloat16* qbuf   = (__hip_bfloat16*)alloc(25165824);
    __hip_bfloat16* aout   = (__hip_bfloat16*)alloc(16777216);

    // 0) detect dtype; convert all 9 inputs
    detect_fp32<<<1, 64, 0, stream>>>((const unsigned short*)P[0], flag);
    ConvDesc cd;
    cd.src[0] = P[0]; cd.dst[0] = xc;                  cd.n8[0] = 8388608 / 8;
    cd.src[1] = P[4]; cd.dst[1] = wfused;              cd.n8[1] = 1179648 / 8;
    cd.src[2] = P[1]; cd.dst[2] = wfused + 576LL*2048; cd.n8[2] = 3145728 / 8;
    cd.src[3] = P[2]; cd.dst[3] = qlnwc;               cd.n8[3] = 1536 / 8;
    cd.src[4] = P[3]; cd.dst[4] = wqbc;                cd.n8[4] = 4718592 / 8;
    cd.src[5] = P[5]; cd.dst[5] = kvlnwc;              cd.n8[5] = 512 / 8;
    cd.src[6] = P[6]; cd.dst[6] = wembc;               cd.n8[6] = 1048576 / 8;
    cd.src[7] = P[7]; cd.dst[7] = wunec;               cd.n8[7] = 1048576 / 8;
    cd.src[8] = P[8]; cd.dst[8] = woc;                 cd.n8[8] = 4194304 / 8;
    conv_all<<<dim3(512, 9), 256, 0, stream>>>(cd, flag);

    // 1) cq = x @ [wkv_a; wq_a]^T   (4096, 2112, 2048)
    gemm_bt<<<dim3(17, 32, 1), 256, 0, stream>>>(
        xc, wfused, cq, 4096, 2112, 2048, 2048, 2048, 2112, 1.0f,
        1, 1, 0, 1, 1, 0, 0, flag, 0, 0);
    // 2) kv latent norm + k_pe rope
    kv_norm_rope<<<1024, 256, 0, stream>>>(cq, kvlnwc, kvl, kpe);
    // 3) wBk = embed^T
    transpose_embed<<<dim3(8, 16), 256, 0, stream>>>(wembc, wBk);
    // 4) K-expand: kvK = kvl[b] @ wBk[h]^T  (2048,128,512) per (b,h)
    gemm_bt<<<dim3(1, 16, 32), 256, 0, stream>>>(
        kvl, wBk, kvK, 2048, 128, 512, 512, 512, 128, 1.0f,
        16, 2, (long long)L_SEQ * KVLR, 1, 16, 128LL * KVLR,
        (long long)L_SEQ * 128, flag, 0, 0);
    // 5) V-expand transposed: kvVt = wune[h] @ kvl[b]^T  (128,2048,512)
    gemm_bt<<<dim3(16, 1, 32), 256, 0, stream>>>(
        wunec, kvl, kvVt, 128, 2048, 512, 512, 512, 2048, 1.0f,
        1, 16, 128LL * KVLR, 16, 2, (long long)L_SEQ * KVLR,
        128LL * L_SEQ, flag, 0, 0);
    // 6) rmsnorm(q_a) in place (cq cols 576..2111)
    rmsnorm_qa<<<4096, 256, 0, stream>>>(cq + 576, qlnwc, 2112);
    // 7) q = rmsnorm(q_a) @ wq_b^T * (SQ*SCALE*log2e), rope fused
    gemm_bt<<<dim3(24, 32, 1), 256, 0, stream>>>(
        cq + 576, wqbc, qbuf, 4096, 3072, 1536, 2112, 1536, 3072,
        0.1202245867417521f,   // (1/12) * log2(e)
        1, 1, 0, 1, 1, 0, 0, flag, 0, 1);
    // 8) split-K flash attention -> fp32 partials (overlaying dead region A)
    flash_attn<<<dim3(48, 32), 256, 0, stream>>>(
        qbuf, kvK, kvVt, kpe, O0, O1, L0, L1);
    // 8b) combine partials -> aout (bf16)
    combine_o<<<4096, 256, 0, stream>>>(O0, O1, L0, L1, aout);
    // 9) out = aout @ wo^T  (fp32 out if inputs were fp32)
    gemm_bt<<<dim3(16, 32, 1), 256, 0, stream>>>(
        aout, woc, (void*)d_out, 4096, 2048, 2048, 2048, 2048, 2048, 1.0f,
        1, 1, 0, 1, 1, 0, 0, flag, 1, 0);
}

// Round 7
// 536.998 us; speedup vs baseline: 5.0091x; 5.0091x over previous
//
#include <hip/hip_runtime.h>
#include <hip/hip_bf16.h>

// Problem constants
#define B_SZ   2
#define L_SEQ  2048
#define HIDD   2048
#define NH     16
#define QL     1536
#define KVLR   512
#define ROPE_D 64
#define NOPE_D 128
#define VD     128
#define QKD    192   // NOPE + ROPE

typedef __attribute__((ext_vector_type(8))) __bf16 bf16x8;
typedef __attribute__((ext_vector_type(4))) float  f32x4;
typedef __attribute__((ext_vector_type(8))) unsigned short u16x8;

#if __has_builtin(__builtin_amdgcn_exp2f)
#define EXP2(x) __builtin_amdgcn_exp2f(x)
#else
#define EXP2(x) exp2f(x)
#endif

__device__ __forceinline__ float bf2f(unsigned short u) {
    union { float f; unsigned int i; } x; x.i = ((unsigned int)u) << 16; return x.f;
}
__device__ __forceinline__ unsigned short f2bf(float f) {
    __hip_bfloat16 h = __float2bfloat16(f);
    return *reinterpret_cast<unsigned short*>(&h);
}
__device__ __forceinline__ float finclamp(float v) {
    return fminf(fmaxf(v, -3.3e38f), 3.3e38f);
}

// async global->LDS, 16B per lane; LDS dest = wave-uniform base + lane*16.
__device__ __forceinline__ void gld_lds16(const __hip_bfloat16* g, __hip_bfloat16* l)
{
    __builtin_amdgcn_global_load_lds(
        (const __attribute__((address_space(1))) unsigned int*)(g),
        (__attribute__((address_space(3))) unsigned int*)(l),
        16, 0, 0);
}

// ---------------------------------------------------------------------------
__global__ void detect_fp32(const unsigned short* __restrict__ x, int* __restrict__ flag)
{
    if (threadIdx.x == 0 && blockIdx.x == 0) {
        int c = 0;
        for (int i = 0; i < 128; i++) {
            unsigned e = (x[2 * i] >> 7) & 0xFF;
            if (e > 150 || (e > 0 && e < 100)) c++;
        }
        *flag = (c >= 16) ? 1 : 0;
    }
}

// ---------------------------------------------------------------------------
struct ConvDesc {
    const void* src[9];
    __hip_bfloat16* dst[9];
    long long n8[9];
};

__global__ __launch_bounds__(256)
void conv_all(ConvDesc d, const int* __restrict__ flag)
{
    const int seg = blockIdx.y;
    const void* src = d.src[seg];
    __hip_bfloat16* dst = d.dst[seg];
    const long long n8 = d.n8[seg];
    const int isf = *flag;
    long long stride = (long long)gridDim.x * 256;
    for (long long i = (long long)blockIdx.x * 256 + threadIdx.x; i < n8; i += stride) {
        u16x8 o;
        if (isf) {
            const float* s = (const float*)src + i * 8;
            float4 a = *(const float4*)s;
            float4 b = *(const float4*)(s + 4);
            o[0] = f2bf(a.x); o[1] = f2bf(a.y); o[2] = f2bf(a.z); o[3] = f2bf(a.w);
            o[4] = f2bf(b.x); o[5] = f2bf(b.y); o[6] = f2bf(b.z); o[7] = f2bf(b.w);
        } else {
            o = ((const u16x8*)src)[i];
        }
        ((u16x8*)dst)[i] = o;
    }
}

// ---------------------------------------------------------------------------
// C = scale*(A.B^T), bf16, 128x128 tile, BK=32, global_load_lds staging.
// EXACT round-4 body (measured fast, no spill). Batched over grid.z:
// offA = ((z/dA)%mA)*sA, offB = ((z/dB)%mB)*sB, offC = z*sC.
// NO trig / rope in this kernel -- keeps the register allocator sane.
// ---------------------------------------------------------------------------
__global__ __launch_bounds__(256)
void gemm_bt(const __hip_bfloat16* __restrict__ A,
             const __hip_bfloat16* __restrict__ Bm,
             void* __restrict__ Cv,
             int M, int N, int K, int lda, int ldb, int ldc,
             float scale,
             int dA, int mA, long long sA,
             int dB, int mB, long long sB, long long sC,
             const int* __restrict__ flagp, int fp32out)
{
    int z = blockIdx.z;
    A  += (long long)((z / dA) % mA) * sA;
    Bm += (long long)((z / dB) % mB) * sB;
    const long long coff = (long long)z * sC;

    __shared__ __hip_bfloat16 As[128 * 32];
    __shared__ __hip_bfloat16 Bs[128 * 32];

    const int tid  = threadIdx.x;
    const int lane = tid & 63;
    const int wid  = tid >> 6;
    const int quad = lane >> 4;
    const int l15  = lane & 15;
    const int wm   = (wid >> 1) * 64;
    const int wn   = (wid & 1) * 64;

    const int m0 = blockIdx.y * 128;
    const int n0 = blockIdx.x * 128;

    const int srow = lane >> 2;
    const int scol = (lane & 3) * 8;

    f32x4 acc[4][4] = {};

    for (int k0 = 0; k0 < K; k0 += 32) {
        __syncthreads();
        for (int i = 0; i < 2; i++) {
            int rbase = wid * 32 + i * 16;
            int r = rbase + srow;
            gld_lds16(A + (long long)(m0 + r) * lda + k0 + scol, &As[rbase * 32]);
            int gn = n0 + r; if (gn >= N) gn = N - 1;
            gld_lds16(Bm + (long long)gn * ldb + k0 + scol, &Bs[rbase * 32]);
        }
        __syncthreads();

        bf16x8 af[4], bfv[4];
        for (int mt = 0; mt < 4; mt++)
            af[mt] = *reinterpret_cast<const bf16x8*>(
                &As[(wm + mt * 16 + l15) * 32 + quad * 8]);
        for (int nt = 0; nt < 4; nt++)
            bfv[nt] = *reinterpret_cast<const bf16x8*>(
                &Bs[(wn + nt * 16 + l15) * 32 + quad * 8]);
        for (int mt = 0; mt < 4; mt++)
            for (int nt = 0; nt < 4; nt++)
                acc[mt][nt] = __builtin_amdgcn_mfma_f32_16x16x32_bf16(
                    af[mt], bfv[nt], acc[mt][nt], 0, 0, 0);
    }

    const int f32o = fp32out && (*flagp);

    // Epilogue: C/D layout col=lane&15, row=quad*4+reg
    for (int mt = 0; mt < 4; mt++) {
        int row = m0 + wm + mt * 16 + quad * 4;
        for (int nt = 0; nt < 4; nt++) {
            int col = n0 + wn + nt * 16 + l15;
            if (col < N) {
                for (int r = 0; r < 4; r++) {
                    float val = finclamp(acc[mt][nt][r] * scale);
                    long long idx = coff + (long long)(row + r) * ldc + col;
                    if (f32o) ((float*)Cv)[idx] = val;
                    else      ((__hip_bfloat16*)Cv)[idx] = __float2bfloat16(val);
                }
            }
        }
    }
}

// ---------------------------------------------------------------------------
// In-place traditional RoPE on q_pe cols h*192+128..191 of qbuf (B*L, 3072).
// Separate kernel: trig stays out of the GEMM binary.
// ---------------------------------------------------------------------------
__global__ __launch_bounds__(256)
void rope_q(__hip_bfloat16* __restrict__ Q)
{
    int row = blockIdx.x;
    int l = row & (L_SEQ - 1);
    int tid = threadIdx.x;
    for (int p = tid; p < NH * 32; p += 256) {
        int h = p >> 5, i = p & 31;
        __hip_bfloat16* base = Q + (long long)row * (NH * QKD) + h * QKD + NOPE_D + 2 * i;
        float freq = exp2f(-(float)i * (13.287712379549449f / 32.0f));
        float th = (float)l * freq;
        float s = __sinf(th), c = __cosf(th);
        float x1 = __bfloat162float(base[0]);
        float x2 = __bfloat162float(base[1]);
        base[0] = __float2bfloat16(finclamp(x1 * c - x2 * s));
        base[1] = __float2bfloat16(finclamp(x1 * s + x2 * c));
    }
}

// ---------------------------------------------------------------------------
__global__ __launch_bounds__(256)
void rmsnorm_qa(__hip_bfloat16* __restrict__ X, const __hip_bfloat16* __restrict__ W,
                int ldx)
{
    int row = blockIdx.x;
    __hip_bfloat16* xr = X + (long long)row * ldx;
    int tid = threadIdx.x;
    bool act = tid < (QL / 8);
    float v[8];
    float ss = 0.f;
    if (act) {
        u16x8 raw = *reinterpret_cast<const u16x8*>(xr + tid * 8);
        for (int j = 0; j < 8; j++) {
            v[j] = bf2f(((const unsigned short*)&raw)[j]);
            ss += v[j] * v[j];
        }
    }
    for (int m = 1; m < 64; m <<= 1) ss += __shfl_xor(ss, m, 64);
    __shared__ float ws4[4];
    if ((tid & 63) == 0) ws4[tid >> 6] = ss;
    __syncthreads();
    float tot = ws4[0] + ws4[1] + ws4[2] + ws4[3];
    float inv = rsqrtf(tot / (float)QL + 1e-5f);
    if (act) {
        u16x8 wr = *reinterpret_cast<const u16x8*>(W + tid * 8);
        u16x8 o;
        for (int j = 0; j < 8; j++)
            ((unsigned short*)&o)[j] =
                f2bf(finclamp(v[j] * inv * bf2f(((const unsigned short*)&wr)[j])));
        *reinterpret_cast<u16x8*>(xr + tid * 8) = o;
    }
}

// ---------------------------------------------------------------------------
__global__ __launch_bounds__(256)
void kv_norm_rope(const __hip_bfloat16* __restrict__ CQ,
                  const __hip_bfloat16* __restrict__ W,
                  __hip_bfloat16* __restrict__ KVLAT,
                  __hip_bfloat16* __restrict__ KPE)
{
    int row = blockIdx.x * 4 + (threadIdx.x >> 6);
    int l = row & (L_SEQ - 1);
    int t = threadIdx.x & 63;
    const __hip_bfloat16* cr = CQ + (long long)row * 2112;

    float v[8]; float ss = 0.f;
    u16x8 raw = *reinterpret_cast<const u16x8*>(cr + t * 8);
    for (int j = 0; j < 8; j++) {
        v[j] = bf2f(((const unsigned short*)&raw)[j]);
        ss += v[j] * v[j];
    }
    for (int m = 1; m < 64; m <<= 1) ss += __shfl_xor(ss, m, 64);
    float inv = rsqrtf(ss / (float)KVLR + 1e-5f) * 2.0f;  // SKV = 2
    u16x8 wr = *reinterpret_cast<const u16x8*>(W + t * 8);
    u16x8 o;
    for (int j = 0; j < 8; j++)
        ((unsigned short*)&o)[j] =
            f2bf(finclamp(v[j] * inv * bf2f(((const unsigned short*)&wr)[j])));
    *reinterpret_cast<u16x8*>(KVLAT + (long long)row * KVLR + t * 8) = o;

    if (t < 32) {
        float freq = exp2f(-(float)t * (13.287712379549449f / 32.0f));
        float th = (float)l * freq;
        float s = __sinf(th), c = __cosf(th);
        float x1 = __bfloat162float(cr[512 + 2 * t]);
        float x2 = __bfloat162float(cr[512 + 2 * t + 1]);
        __hip_bfloat16* kp = KPE + (long long)row * 64;
        kp[2 * t]     = __float2bfloat16(finclamp(x1 * c - x2 * s));
        kp[2 * t + 1] = __float2bfloat16(finclamp(x1 * s + x2 * c));
    }
}

// ---------------------------------------------------------------------------
__global__ __launch_bounds__(256)
void transpose_embed(const __hip_bfloat16* __restrict__ WE,
                     __hip_bfloat16* __restrict__ WB)
{
    int h = blockIdx.y;
    int k0 = blockIdx.x * 64;
    __shared__ __hip_bfloat16 t[64][136];
    int tid = threadIdx.x;
    for (int it = 0; it < 4; it++) {
        int s = tid + it * 256;
        int k = s >> 4, cg = (s & 15) * 8;
        u16x8 v = *reinterpret_cast<const u16x8*>(
            WE + ((long long)h * KVLR + k0 + k) * NOPE_D + cg);
        *reinterpret_cast<u16x8*>(&t[k][cg]) = v;
    }
    __syncthreads();
    for (int it = 0; it < 4; it++) {
        int s = tid + it * 256;
        int n = s >> 3, kg = (s & 7) * 8;
        u16x8 o;
        for (int j = 0; j < 8; j++)
            ((unsigned short*)&o)[j] = *reinterpret_cast<unsigned short*>(&t[kg + j][n]);
        *reinterpret_cast<u16x8*>(WB + ((long long)h * 128 + n) * KVLR + k0 + kg) = o;
    }
}

// ---------------------------------------------------------------------------
// Split-K flash attention, static-max (partials exactly additive).
// Q (B*L,H*192) pre-scaled by SQ*SCALE*log2e, roped. Kb (B*H,L,128);
// Vt (B*H,128,L); KPE (B,L,64).  Grid: x = 48 chunk-units, y = 32 bh.
// Chunk0 = key tiles [0,min(qt+1,16)), chunk1 = [16,qt+1) (qt>=16 only).
// ---------------------------------------------------------------------------
__global__ __launch_bounds__(256)
void flash_attn(const __hip_bfloat16* __restrict__ Q,
                const __hip_bfloat16* __restrict__ Kb,
                const __hip_bfloat16* __restrict__ Vt,
                const __hip_bfloat16* __restrict__ KPE,
                float* __restrict__ O0, float* __restrict__ O1,
                float* __restrict__ L0, float* __restrict__ L1)
{
    const int u = blockIdx.x;
    int qt, ch;
    if (u < 32) { int k = u >> 1; qt = 31 - k; ch = u & 1; }
    else        { qt = 47 - u;    ch = 0; }
    const int q0 = qt * 64;
    const int t0 = ch ? 16 : 0;
    const int t1 = ch ? (qt + 1) : ((qt + 1 < 16) ? (qt + 1) : 16);

    const int bh = blockIdx.y;
    const int b = bh >> 4;
    const int h = bh & 15;

    __shared__ __hip_bfloat16 Ks[64 * 200];
    __shared__ __hip_bfloat16 Vs[128 * 72];
    __shared__ __hip_bfloat16 Ps[4][16 * 72];

    const int tid  = threadIdx.x;
    const int lane = tid & 63;
    const int w    = tid >> 6;
    const int quad = lane >> 4;
    const int l15  = lane & 15;

    const __hip_bfloat16* Kbh  = Kb + (long long)bh * L_SEQ * 128;
    const __hip_bfloat16* Vth  = Vt + (long long)bh * 128 * L_SEQ;
    const __hip_bfloat16* KPEb = KPE + (long long)b * L_SEQ * 64;

    bf16x8 qf[6];
    {
        long long qoff = (long long)(b * L_SEQ + q0 + w * 16 + l15) * (NH * QKD) + h * QKD;
        for (int kk = 0; kk < 6; kk++)
            qf[kk] = *reinterpret_cast<const bf16x8*>(Q + qoff + kk * 32 + quad * 8);
    }

    f32x4 o_acc[8] = {};
    float l_run[4] = {0.f, 0.f, 0.f, 0.f};

    for (int kt = t0; kt < t1; kt++) {
        const int kk0 = kt * 64;
        const bool partial = (kt == qt);     // diagonal tile only
        __syncthreads();
        for (int it = 0; it < 6; it++) {
            int s = tid + it * 256;
            int r = s / 24, cg = s % 24;
            u16x8 v;
            if (cg < 16)
                v = *reinterpret_cast<const u16x8*>(
                    Kbh + (long long)(kk0 + r) * 128 + cg * 8);
            else
                v = *reinterpret_cast<const u16x8*>(
                    KPEb + (long long)(kk0 + r) * 64 + (cg - 16) * 8);
            *reinterpret_cast<u16x8*>(&Ks[r * 200 + cg * 8]) = v;
        }
        for (int it = 0; it < 4; it++) {
            int s = tid + it * 256;
            int vd = s >> 3, kg = (s & 7) * 8;
            u16x8 v = *reinterpret_cast<const u16x8*>(
                Vth + (long long)vd * L_SEQ + kk0 + kg);
            *reinterpret_cast<u16x8*>(&Vs[vd * 72 + kg]) = v;
        }
        __syncthreads();

        // S' = (Q*log2e) . K^T
        f32x4 sfr[4];
        for (int nt = 0; nt < 4; nt++) {
            f32x4 sacc = {};
            for (int kk = 0; kk < 6; kk++) {
                bf16x8 kf = *reinterpret_cast<const bf16x8*>(
                    &Ks[(nt * 16 + l15) * 200 + kk * 32 + quad * 8]);
                sacc = __builtin_amdgcn_mfma_f32_16x16x32_bf16(qf[kk], kf, sacc, 0, 0, 0);
            }
            sfr[nt] = sacc;
        }

        // p = 2^(S'); causal mask only on the diagonal tile
        const int qrow_base = q0 + w * 16 + quad * 4;
        float rs[4] = {0.f, 0.f, 0.f, 0.f};
        if (partial) {
            for (int nt = 0; nt < 4; nt++) {
                int key = kk0 + nt * 16 + l15;
                for (int r = 0; r < 4; r++) {
                    float p = (key > qrow_base + r) ? 0.f : EXP2(sfr[nt][r]);
                    sfr[nt][r] = p;
                    rs[r] += p;
                }
            }
        } else {
            for (int nt = 0; nt < 4; nt++)
                for (int r = 0; r < 4; r++) {
                    float p = EXP2(sfr[nt][r]);
                    sfr[nt][r] = p;
                    rs[r] += p;
                }
        }

        // P -> LDS first (write latency overlaps the shuffle-reduce below)
        for (int nt = 0; nt < 4; nt++)
            for (int r = 0; r < 4; r++)
                Ps[w][(quad * 4 + r) * 72 + nt * 16 + l15] =
                    __float2bfloat16(sfr[nt][r]);

        for (int r = 0; r < 4; r++) {
            float t = rs[r];
            for (int m = 1; m < 16; m <<= 1) t += __shfl_xor(t, m, 16);
            l_run[r] += t;
        }

        // O += P . V
        for (int ks = 0; ks < 2; ks++) {
            bf16x8 pf = *reinterpret_cast<const bf16x8*>(
                &Ps[w][l15 * 72 + ks * 32 + quad * 8]);
            for (int vt = 0; vt < 8; vt++) {
                bf16x8 vf = *reinterpret_cast<const bf16x8*>(
                    &Vs[(vt * 16 + l15) * 72 + ks * 32 + quad * 8]);
                o_acc[vt] = __builtin_amdgcn_mfma_f32_16x16x32_bf16(pf, vf, o_acc[vt], 0, 0, 0);
            }
        }
    }

    // epilogue: unnormalized fp32 partials
    const int orow = q0 + w * 16 + quad * 4;
    float* Op; float* Lp; long long rbase;
    if (ch == 0) { Op = O0; Lp = L0; rbase = (long long)b * 2048 + orow; }
    else         { Op = O1; Lp = L1; rbase = (long long)b * 1024 + (orow - 1024); }
    for (int r = 0; r < 4; r++) {
        float* op = Op + (rbase + r) * 2048 + h * 128;
        for (int vt = 0; vt < 8; vt++)
            op[vt * 16 + l15] = o_acc[vt][r];
        if (l15 == 0) Lp[(rbase + r) * 16 + h] = l_run[r];
    }
}

// ---------------------------------------------------------------------------
// Combine: aout = (O0 [+ O1]) / (l0 [+ l1]), bf16. grid = 4096 rows.
// ---------------------------------------------------------------------------
__global__ __launch_bounds__(256)
void combine_o(const float* __restrict__ O0, const float* __restrict__ O1,
               const float* __restrict__ L0, const float* __restrict__ L1,
               __hip_bfloat16* __restrict__ aout)
{
    const int row = blockIdx.x;
    const int rl = row & 2047;
    const int b = row >> 11;
    const bool has1 = rl >= 1024;
    const long long rowc = (long long)b * 1024 + (rl - 1024);
    const float* o0 = O0 + (long long)row * 2048;
    const float* o1 = O1 + rowc * 2048;
    const int tid = threadIdx.x;
    const int c0 = tid * 8;
    const int h = c0 >> 7;
    float l = L0[(long long)row * 16 + h] + (has1 ? L1[rowc * 16 + h] : 0.f);
    float inv = 1.0f / fmaxf(l, 1e-30f);
    float4 a = *(const float4*)(o0 + c0);
    float4 bb = *(const float4*)(o0 + c0 + 4);
    if (has1) {
        float4 c = *(const float4*)(o1 + c0);
        float4 d = *(const float4*)(o1 + c0 + 4);
        a.x += c.x; a.y += c.y; a.z += c.z; a.w += c.w;
        bb.x += d.x; bb.y += d.y; bb.z += d.z; bb.w += d.w;
    }
    u16x8 o;
    o[0] = f2bf(finclamp(a.x * inv));  o[1] = f2bf(finclamp(a.y * inv));
    o[2] = f2bf(finclamp(a.z * inv));  o[3] = f2bf(finclamp(a.w * inv));
    o[4] = f2bf(finclamp(bb.x * inv)); o[5] = f2bf(finclamp(bb.y * inv));
    o[6] = f2bf(finclamp(bb.z * inv)); o[7] = f2bf(finclamp(bb.w * inv));
    *reinterpret_cast<u16x8*>(aout + (long long)row * 2048 + c0) = o;
}

// ---------------------------------------------------------------------------
extern "C" void kernel_launch(void* const* d_in, const int* in_sizes, int n_in,
                              void* d_out, int out_size, void* d_ws, size_t ws_size,
                              hipStream_t stream)
{
    const long long want[9] = {
        8388608, 3145728, 1536, 4718592, 1179648, 512, 1048576, 1048576, 4194304
    };
    const void* P[9] = {};
    {
        int j = 0;
        for (int i = 0; i < n_in && j < 9; i++)
            if ((long long)in_sizes[i] == want[j]) P[j++] = d_in[i];
        if (!P[8]) {
            const int map[9] = {0, 2, 3, 4, 5, 6, 7, 8, 9};
            for (int j2 = 0; j2 < 9; j2++) P[j2] = d_in[map[j2]];
        }
    }
    (void)ws_size; (void)out_size;

    char* ws = (char*)d_ws;
    int* flag = (int*)ws;
    char* A = ws + 256;

    // Region A: dead after step 7 (q_b GEMM); overlaid by fp32 flash partials
    __hip_bfloat16* xc     = (__hip_bfloat16*)(A);              // 16,777,216
    __hip_bfloat16* wfused = (__hip_bfloat16*)(A + 16777216);   //  8,650,752
    __hip_bfloat16* wqbc   = (__hip_bfloat16*)(A + 25427968);   //  9,437,184
    __hip_bfloat16* cq     = (__hip_bfloat16*)(A + 34865152);   // 17,301,504 -> A ends 52,166,656
    float* O0 = (float*)(A);                                    // 33,554,432
    float* O1 = (float*)(A + 33554432);                         // 16,777,216
    float* L0 = (float*)(A + 50331648);                         //    262,144
    float* L1 = (float*)(A + 50593792);                         //    131,072

    long long off = 256 + 52166656;
    auto alloc = [&](long long bytes) {
        char* p = ws + off;
        off += ((bytes + 255) / 256) * 256;
        return p;
    };
    __hip_bfloat16* qlnwc  = (__hip_bfloat16*)alloc(3072);
    __hip_bfloat16* kvlnwc = (__hip_bfloat16*)alloc(1024);
    __hip_bfloat16* wembc  = (__hip_bfloat16*)alloc(2097152);
    __hip_bfloat16* wunec  = (__hip_bfloat16*)alloc(2097152);
    __hip_bfloat16* woc    = (__hip_bfloat16*)alloc(8388608);
    __hip_bfloat16* kvl    = (__hip_bfloat16*)alloc(4194304);
    __hip_bfloat16* kpe    = (__hip_bfloat16*)alloc(524288);
    __hip_bfloat16* wBk    = (__hip_bfloat16*)alloc(2097152);
    __hip_bfloat16* kvK    = (__hip_bfloat16*)alloc(16777216);
    __hip_bfloat16* kvVt   = (__hip_bfloat16*)alloc(16777216);
    __hip_bfloat16* qbuf   = (__hip_bfloat16*)alloc(25165824);
    __hip_bfloat16* aout   = (__hip_bfloat16*)alloc(16777216);

    // 0) detect dtype; convert all 9 inputs
    detect_fp32<<<1, 64, 0, stream>>>((const unsigned short*)P[0], flag);
    ConvDesc cd;
    cd.src[0] = P[0]; cd.dst[0] = xc;                  cd.n8[0] = 8388608 / 8;
    cd.src[1] = P[4]; cd.dst[1] = wfused;              cd.n8[1] = 1179648 / 8;
    cd.src[2] = P[1]; cd.dst[2] = wfused + 576LL*2048; cd.n8[2] = 3145728 / 8;
    cd.src[3] = P[2]; cd.dst[3] = qlnwc;               cd.n8[3] = 1536 / 8;
    cd.src[4] = P[3]; cd.dst[4] = wqbc;                cd.n8[4] = 4718592 / 8;
    cd.src[5] = P[5]; cd.dst[5] = kvlnwc;              cd.n8[5] = 512 / 8;
    cd.src[6] = P[6]; cd.dst[6] = wembc;               cd.n8[6] = 1048576 / 8;
    cd.src[7] = P[7]; cd.dst[7] = wunec;               cd.n8[7] = 1048576 / 8;
    cd.src[8] = P[8]; cd.dst[8] = woc;                 cd.n8[8] = 4194304 / 8;
    conv_all<<<dim3(512, 9), 256, 0, stream>>>(cd, flag);

    // 1) cq = x @ [wkv_a; wq_a]^T   (4096, 2112, 2048)
    gemm_bt<<<dim3(17, 32, 1), 256, 0, stream>>>(
        xc, wfused, cq, 4096, 2112, 2048, 2048, 2048, 2112, 1.0f,
        1, 1, 0, 1, 1, 0, 0, flag, 0);
    // 2) kv latent norm + k_pe rope
    kv_norm_rope<<<1024, 256, 0, stream>>>(cq, kvlnwc, kvl, kpe);
    // 3) wBk = embed^T
    transpose_embed<<<dim3(8, 16), 256, 0, stream>>>(wembc, wBk);
    // 4) K-expand: kvK = kvl[b] @ wBk[h]^T  (2048,128,512) per (b,h)
    gemm_bt<<<dim3(1, 16, 32), 256, 0, stream>>>(
        kvl, wBk, kvK, 2048, 128, 512, 512, 512, 128, 1.0f,
        16, 2, (long long)L_SEQ * KVLR, 1, 16, 128LL * KVLR,
        (long long)L_SEQ * 128, flag, 0);
    // 5) V-expand transposed: kvVt = wune[h] @ kvl[b]^T  (128,2048,512)
    gemm_bt<<<dim3(16, 1, 32), 256, 0, stream>>>(
        wunec, kvl, kvVt, 128, 2048, 512, 512, 512, 2048, 1.0f,
        1, 16, 128LL * KVLR, 16, 2, (long long)L_SEQ * KVLR,
        128LL * L_SEQ, flag, 0);
    // 6) rmsnorm(q_a) in place (cq cols 576..2111)
    rmsnorm_qa<<<4096, 256, 0, stream>>>(cq + 576, qlnwc, 2112);
    // 7) q = rmsnorm(q_a) @ wq_b^T * (SQ*SCALE*log2e)
    gemm_bt<<<dim3(24, 32, 1), 256, 0, stream>>>(
        cq + 576, wqbc, qbuf, 4096, 3072, 1536, 2112, 1536, 3072,
        0.1202245867417521f,   // (1/12) * log2(e)
        1, 1, 0, 1, 1, 0, 0, flag, 0);
    // 7b) rope q_pe in place (separate kernel; rotation commutes with scale)
    rope_q<<<4096, 256, 0, stream>>>(qbuf);
    // 8) split-K flash attention -> fp32 partials (overlaying dead region A)
    flash_attn<<<dim3(48, 32), 256, 0, stream>>>(
        qbuf, kvK, kvVt, kpe, O0, O1, L0, L1);
    // 8b) combine partials -> aout (bf16)
    combine_o<<<4096, 256, 0, stream>>>(O0, O1, L0, L1, aout);
    // 9) out = aout @ wo^T  (fp32 out if inputs were fp32)
    gemm_bt<<<dim3(16, 32, 1), 256, 0, stream>>>(
        aout, woc, (void*)d_out, 4096, 2048, 2048, 2048, 2048, 2048, 1.0f,
        1, 1, 0, 1, 1, 0, 0, flag, 1);
}

// Round 8
// 530.717 us; speedup vs baseline: 5.0684x; 1.0118x over previous
//
#include <hip/hip_runtime.h>
#include <hip/hip_bf16.h>

// Problem constants
#define B_SZ   2
#define L_SEQ  2048
#define HIDD   2048
#define NH     16
#define QL     1536
#define KVLR   512
#define ROPE_D 64
#define NOPE_D 128
#define VD     128
#define QKD    192   // NOPE + ROPE

typedef __attribute__((ext_vector_type(8))) __bf16 bf16x8;
typedef __attribute__((ext_vector_type(4))) float  f32x4;
typedef __attribute__((ext_vector_type(8))) unsigned short u16x8;

#if __has_builtin(__builtin_amdgcn_exp2f)
#define EXP2(x) __builtin_amdgcn_exp2f(x)
#else
#define EXP2(x) exp2f(x)
#endif

__device__ __forceinline__ float bf2f(unsigned short u) {
    union { float f; unsigned int i; } x; x.i = ((unsigned int)u) << 16; return x.f;
}
__device__ __forceinline__ unsigned short f2bf(float f) {
    __hip_bfloat16 h = __float2bfloat16(f);
    return *reinterpret_cast<unsigned short*>(&h);
}
__device__ __forceinline__ float finclamp(float v) {
    return fminf(fmaxf(v, -3.3e38f), 3.3e38f);
}

// async global->LDS, 16B per lane; LDS dest = wave-uniform base + lane*16.
__device__ __forceinline__ void gld_lds16(const __hip_bfloat16* g, __hip_bfloat16* l)
{
    __builtin_amdgcn_global_load_lds(
        (const __attribute__((address_space(1))) unsigned int*)(g),
        (__attribute__((address_space(3))) unsigned int*)(l),
        16, 0, 0);
}

// ---------------------------------------------------------------------------
__global__ void detect_fp32(const unsigned short* __restrict__ x, int* __restrict__ flag)
{
    if (threadIdx.x == 0 && blockIdx.x == 0) {
        int c = 0;
        for (int i = 0; i < 128; i++) {
            unsigned e = (x[2 * i] >> 7) & 0xFF;
            if (e > 150 || (e > 0 && e < 100)) c++;
        }
        *flag = (c >= 16) ? 1 : 0;
    }
}

// ---------------------------------------------------------------------------
struct ConvDesc {
    const void* src[9];
    __hip_bfloat16* dst[9];
    long long n8[9];
};

__global__ __launch_bounds__(256)
void conv_all(ConvDesc d, const int* __restrict__ flag)
{
    const int seg = blockIdx.y;
    const void* src = d.src[seg];
    __hip_bfloat16* dst = d.dst[seg];
    const long long n8 = d.n8[seg];
    const int isf = *flag;
    long long stride = (long long)gridDim.x * 256;
    for (long long i = (long long)blockIdx.x * 256 + threadIdx.x; i < n8; i += stride) {
        u16x8 o;
        if (isf) {
            const float* s = (const float*)src + i * 8;
            float4 a = *(const float4*)s;
            float4 b = *(const float4*)(s + 4);
            o[0] = f2bf(a.x); o[1] = f2bf(a.y); o[2] = f2bf(a.z); o[3] = f2bf(a.w);
            o[4] = f2bf(b.x); o[5] = f2bf(b.y); o[6] = f2bf(b.z); o[7] = f2bf(b.w);
        } else {
            o = ((const u16x8*)src)[i];
        }
        ((u16x8*)dst)[i] = o;
    }
}

// ---------------------------------------------------------------------------
// C = scale*(A.B^T), bf16, 128x128 tile, BK=32, global_load_lds staging.
// EXACT round-4 body (measured fast, no spill). Batched over grid.z.
// NO trig / rope in this kernel -- keeps the register allocator sane.
// ---------------------------------------------------------------------------
__global__ __launch_bounds__(256)
void gemm_bt(const __hip_bfloat16* __restrict__ A,
             const __hip_bfloat16* __restrict__ Bm,
             void* __restrict__ Cv,
             int M, int N, int K, int lda, int ldb, int ldc,
             float scale,
             int dA, int mA, long long sA,
             int dB, int mB, long long sB, long long sC,
             const int* __restrict__ flagp, int fp32out)
{
    int z = blockIdx.z;
    A  += (long long)((z / dA) % mA) * sA;
    Bm += (long long)((z / dB) % mB) * sB;
    const long long coff = (long long)z * sC;

    __shared__ __hip_bfloat16 As[128 * 32];
    __shared__ __hip_bfloat16 Bs[128 * 32];

    const int tid  = threadIdx.x;
    const int lane = tid & 63;
    const int wid  = tid >> 6;
    const int quad = lane >> 4;
    const int l15  = lane & 15;
    const int wm   = (wid >> 1) * 64;
    const int wn   = (wid & 1) * 64;

    const int m0 = blockIdx.y * 128;
    const int n0 = blockIdx.x * 128;

    const int srow = lane >> 2;
    const int scol = (lane & 3) * 8;

    f32x4 acc[4][4] = {};

    for (int k0 = 0; k0 < K; k0 += 32) {
        __syncthreads();
        for (int i = 0; i < 2; i++) {
            int rbase = wid * 32 + i * 16;
            int r = rbase + srow;
            gld_lds16(A + (long long)(m0 + r) * lda + k0 + scol, &As[rbase * 32]);
            int gn = n0 + r; if (gn >= N) gn = N - 1;
            gld_lds16(Bm + (long long)gn * ldb + k0 + scol, &Bs[rbase * 32]);
        }
        __syncthreads();

        bf16x8 af[4], bfv[4];
        for (int mt = 0; mt < 4; mt++)
            af[mt] = *reinterpret_cast<const bf16x8*>(
                &As[(wm + mt * 16 + l15) * 32 + quad * 8]);
        for (int nt = 0; nt < 4; nt++)
            bfv[nt] = *reinterpret_cast<const bf16x8*>(
                &Bs[(wn + nt * 16 + l15) * 32 + quad * 8]);
        for (int mt = 0; mt < 4; mt++)
            for (int nt = 0; nt < 4; nt++)
                acc[mt][nt] = __builtin_amdgcn_mfma_f32_16x16x32_bf16(
                    af[mt], bfv[nt], acc[mt][nt], 0, 0, 0);
    }

    const int f32o = fp32out && (*flagp);

    for (int mt = 0; mt < 4; mt++) {
        int row = m0 + wm + mt * 16 + quad * 4;
        for (int nt = 0; nt < 4; nt++) {
            int col = n0 + wn + nt * 16 + l15;
            if (col < N) {
                for (int r = 0; r < 4; r++) {
                    float val = finclamp(acc[mt][nt][r] * scale);
                    long long idx = coff + (long long)(row + r) * ldc + col;
                    if (f32o) ((float*)Cv)[idx] = val;
                    else      ((__hip_bfloat16*)Cv)[idx] = __float2bfloat16(val);
                }
            }
        }
    }
}

// ---------------------------------------------------------------------------
// In-place traditional RoPE on q_pe cols h*192+128..191 of qbuf (B*L, 3072).
// ---------------------------------------------------------------------------
__global__ __launch_bounds__(256)
void rope_q(__hip_bfloat16* __restrict__ Q)
{
    int row = blockIdx.x;
    int l = row & (L_SEQ - 1);
    int tid = threadIdx.x;
    for (int p = tid; p < NH * 32; p += 256) {
        int h = p >> 5, i = p & 31;
        __hip_bfloat16* base = Q + (long long)row * (NH * QKD) + h * QKD + NOPE_D + 2 * i;
        float freq = exp2f(-(float)i * (13.287712379549449f / 32.0f));
        float th = (float)l * freq;
        float s = __sinf(th), c = __cosf(th);
        float x1 = __bfloat162float(base[0]);
        float x2 = __bfloat162float(base[1]);
        base[0] = __float2bfloat16(finclamp(x1 * c - x2 * s));
        base[1] = __float2bfloat16(finclamp(x1 * s + x2 * c));
    }
}

// ---------------------------------------------------------------------------
__global__ __launch_bounds__(256)
void rmsnorm_qa(__hip_bfloat16* __restrict__ X, const __hip_bfloat16* __restrict__ W,
                int ldx)
{
    int row = blockIdx.x;
    __hip_bfloat16* xr = X + (long long)row * ldx;
    int tid = threadIdx.x;
    bool act = tid < (QL / 8);
    float v[8];
    float ss = 0.f;
    if (act) {
        u16x8 raw = *reinterpret_cast<const u16x8*>(xr + tid * 8);
        for (int j = 0; j < 8; j++) {
            v[j] = bf2f(((const unsigned short*)&raw)[j]);
            ss += v[j] * v[j];
        }
    }
    for (int m = 1; m < 64; m <<= 1) ss += __shfl_xor(ss, m, 64);
    __shared__ float ws4[4];
    if ((tid & 63) == 0) ws4[tid >> 6] = ss;
    __syncthreads();
    float tot = ws4[0] + ws4[1] + ws4[2] + ws4[3];
    float inv = rsqrtf(tot / (float)QL + 1e-5f);
    if (act) {
        u16x8 wr = *reinterpret_cast<const u16x8*>(W + tid * 8);
        u16x8 o;
        for (int j = 0; j < 8; j++)
            ((unsigned short*)&o)[j] =
                f2bf(finclamp(v[j] * inv * bf2f(((const unsigned short*)&wr)[j])));
        *reinterpret_cast<u16x8*>(xr + tid * 8) = o;
    }
}

// ---------------------------------------------------------------------------
__global__ __launch_bounds__(256)
void kv_norm_rope(const __hip_bfloat16* __restrict__ CQ,
                  const __hip_bfloat16* __restrict__ W,
                  __hip_bfloat16* __restrict__ KVLAT,
                  __hip_bfloat16* __restrict__ KPE)
{
    int row = blockIdx.x * 4 + (threadIdx.x >> 6);
    int l = row & (L_SEQ - 1);
    int t = threadIdx.x & 63;
    const __hip_bfloat16* cr = CQ + (long long)row * 2112;

    float v[8]; float ss = 0.f;
    u16x8 raw = *reinterpret_cast<const u16x8*>(cr + t * 8);
    for (int j = 0; j < 8; j++) {
        v[j] = bf2f(((const unsigned short*)&raw)[j]);
        ss += v[j] * v[j];
    }
    for (int m = 1; m < 64; m <<= 1) ss += __shfl_xor(ss, m, 64);
    float inv = rsqrtf(ss / (float)KVLR + 1e-5f) * 2.0f;  // SKV = 2
    u16x8 wr = *reinterpret_cast<const u16x8*>(W + t * 8);
    u16x8 o;
    for (int j = 0; j < 8; j++)
        ((unsigned short*)&o)[j] =
            f2bf(finclamp(v[j] * inv * bf2f(((const unsigned short*)&wr)[j])));
    *reinterpret_cast<u16x8*>(KVLAT + (long long)row * KVLR + t * 8) = o;

    if (t < 32) {
        float freq = exp2f(-(float)t * (13.287712379549449f / 32.0f));
        float th = (float)l * freq;
        float s = __sinf(th), c = __cosf(th);
        float x1 = __bfloat162float(cr[512 + 2 * t]);
        float x2 = __bfloat162float(cr[512 + 2 * t + 1]);
        __hip_bfloat16* kp = KPE + (long long)row * 64;
        kp[2 * t]     = __float2bfloat16(finclamp(x1 * c - x2 * s));
        kp[2 * t + 1] = __float2bfloat16(finclamp(x1 * s + x2 * c));
    }
}

// ---------------------------------------------------------------------------
__global__ __launch_bounds__(256)
void transpose_embed(const __hip_bfloat16* __restrict__ WE,
                     __hip_bfloat16* __restrict__ WB)
{
    int h = blockIdx.y;
    int k0 = blockIdx.x * 64;
    __shared__ __hip_bfloat16 t[64][136];
    int tid = threadIdx.x;
    for (int it = 0; it < 4; it++) {
        int s = tid + it * 256;
        int k = s >> 4, cg = (s & 15) * 8;
        u16x8 v = *reinterpret_cast<const u16x8*>(
            WE + ((long long)h * KVLR + k0 + k) * NOPE_D + cg);
        *reinterpret_cast<u16x8*>(&t[k][cg]) = v;
    }
    __syncthreads();
    for (int it = 0; it < 4; it++) {
        int s = tid + it * 256;
        int n = s >> 3, kg = (s & 7) * 8;
        u16x8 o;
        for (int j = 0; j < 8; j++)
            ((unsigned short*)&o)[j] = *reinterpret_cast<unsigned short*>(&t[kg + j][n]);
        *reinterpret_cast<u16x8*>(WB + ((long long)h * 128 + n) * KVLR + k0 + kg) = o;
    }
}

// ---------------------------------------------------------------------------
// 4-way split-K flash attention, static-max (partials exactly additive).
// Chunk c covers key tiles [8c, min(qt+1, 8c+8)); exists for qt >= 8c.
// Partials: bf16 unnormalized O + fp32 l, compact row layout:
//   chunk c holds rows rl in [512c, 2048) for each b:
//   rbase = pfx[c] + b*(2048-512c) + (rl-512c),  pfx = {0,4096,7168,9216}.
// Grid x = 80 (c0:32 qt desc, c1:24, c2:16, c3:8), y = 32 bh.
// ---------------------------------------------------------------------------
__global__ __launch_bounds__(256)
void flash_attn(const __hip_bfloat16* __restrict__ Q,
                const __hip_bfloat16* __restrict__ Kb,
                const __hip_bfloat16* __restrict__ Vt,
                const __hip_bfloat16* __restrict__ KPE,
                __hip_bfloat16* __restrict__ OP,
                float* __restrict__ LP)
{
    const int u = blockIdx.x;
    int c, qt;
    if (u < 32)      { c = 0; qt = 31 - u; }
    else if (u < 56) { c = 1; qt = 31 - (u - 32); }
    else if (u < 72) { c = 2; qt = 31 - (u - 56); }
    else             { c = 3; qt = 31 - (u - 72); }
    const int q0 = qt * 64;
    const int t0 = c * 8;
    const int t1 = (qt + 1 < t0 + 8) ? (qt + 1) : (t0 + 8);

    const int bh = blockIdx.y;
    const int b = bh >> 4;
    const int h = bh & 15;

    __shared__ __hip_bfloat16 Ks[64 * 200];
    __shared__ __hip_bfloat16 Vs[128 * 72];
    __shared__ __hip_bfloat16 Ps[4][16 * 72];

    const int tid  = threadIdx.x;
    const int lane = tid & 63;
    const int w    = tid >> 6;
    const int quad = lane >> 4;
    const int l15  = lane & 15;

    const __hip_bfloat16* Kbh  = Kb + (long long)bh * L_SEQ * 128;
    const __hip_bfloat16* Vth  = Vt + (long long)bh * 128 * L_SEQ;
    const __hip_bfloat16* KPEb = KPE + (long long)b * L_SEQ * 64;

    bf16x8 qf[6];
    {
        long long qoff = (long long)(b * L_SEQ + q0 + w * 16 + l15) * (NH * QKD) + h * QKD;
        for (int kk = 0; kk < 6; kk++)
            qf[kk] = *reinterpret_cast<const bf16x8*>(Q + qoff + kk * 32 + quad * 8);
    }

    f32x4 o_acc[8] = {};
    float l_run[4] = {0.f, 0.f, 0.f, 0.f};

    for (int kt = t0; kt < t1; kt++) {
        const int kk0 = kt * 64;
        const bool partial = (kt == qt);     // diagonal tile only
        __syncthreads();
        for (int it = 0; it < 6; it++) {
            int s = tid + it * 256;
            int r = s / 24, cg = s % 24;
            u16x8 v;
            if (cg < 16)
                v = *reinterpret_cast<const u16x8*>(
                    Kbh + (long long)(kk0 + r) * 128 + cg * 8);
            else
                v = *reinterpret_cast<const u16x8*>(
                    KPEb + (long long)(kk0 + r) * 64 + (cg - 16) * 8);
            *reinterpret_cast<u16x8*>(&Ks[r * 200 + cg * 8]) = v;
        }
        for (int it = 0; it < 4; it++) {
            int s = tid + it * 256;
            int vd = s >> 3, kg = (s & 7) * 8;
            u16x8 v = *reinterpret_cast<const u16x8*>(
                Vth + (long long)vd * L_SEQ + kk0 + kg);
            *reinterpret_cast<u16x8*>(&Vs[vd * 72 + kg]) = v;
        }
        __syncthreads();

        // S' = (Q*log2e) . K^T
        f32x4 sfr[4];
        for (int nt = 0; nt < 4; nt++) {
            f32x4 sacc = {};
            for (int kk = 0; kk < 6; kk++) {
                bf16x8 kf = *reinterpret_cast<const bf16x8*>(
                    &Ks[(nt * 16 + l15) * 200 + kk * 32 + quad * 8]);
                sacc = __builtin_amdgcn_mfma_f32_16x16x32_bf16(qf[kk], kf, sacc, 0, 0, 0);
            }
            sfr[nt] = sacc;
        }

        // p = 2^(S'); causal mask only on the diagonal tile
        const int qrow_base = q0 + w * 16 + quad * 4;
        float rs[4] = {0.f, 0.f, 0.f, 0.f};
        if (partial) {
            for (int nt = 0; nt < 4; nt++) {
                int key = kk0 + nt * 16 + l15;
                for (int r = 0; r < 4; r++) {
                    float p = (key > qrow_base + r) ? 0.f : EXP2(sfr[nt][r]);
                    sfr[nt][r] = p;
                    rs[r] += p;
                }
            }
        } else {
            for (int nt = 0; nt < 4; nt++)
                for (int r = 0; r < 4; r++) {
                    float p = EXP2(sfr[nt][r]);
                    sfr[nt][r] = p;
                    rs[r] += p;
                }
        }

        // P -> LDS first (write latency overlaps the shuffle-reduce below)
        for (int nt = 0; nt < 4; nt++)
            for (int r = 0; r < 4; r++)
                Ps[w][(quad * 4 + r) * 72 + nt * 16 + l15] =
                    __float2bfloat16(sfr[nt][r]);

        for (int r = 0; r < 4; r++) {
            float t = rs[r];
            for (int m = 1; m < 16; m <<= 1) t += __shfl_xor(t, m, 16);
            l_run[r] += t;
        }

        // O += P . V
        for (int ks = 0; ks < 2; ks++) {
            bf16x8 pf = *reinterpret_cast<const bf16x8*>(
                &Ps[w][l15 * 72 + ks * 32 + quad * 8]);
            for (int vt = 0; vt < 8; vt++) {
                bf16x8 vf = *reinterpret_cast<const bf16x8*>(
                    &Vs[(vt * 16 + l15) * 72 + ks * 32 + quad * 8]);
                o_acc[vt] = __builtin_amdgcn_mfma_f32_16x16x32_bf16(pf, vf, o_acc[vt], 0, 0, 0);
            }
        }
    }

    // epilogue: unnormalized bf16 O partial + fp32 l
    const int pfx[4] = {0, 4096, 7168, 9216};
    const int orow = q0 + w * 16 + quad * 4;
    const long long rb0 = pfx[c] + (long long)b * (2048 - 512 * c) + (orow - 512 * c);
    for (int r = 0; r < 4; r++) {
        __hip_bfloat16* op = OP + (rb0 + r) * 2048 + h * 128;
        for (int vt = 0; vt < 8; vt++)
            op[vt * 16 + l15] = __float2bfloat16(finclamp(o_acc[vt][r]));
        if (l15 == 0) LP[(rb0 + r) * 16 + h] = l_run[r];
    }
}

// ---------------------------------------------------------------------------
// Combine: aout[row] = sum_c O_c[row] / sum_c l_c[row].  grid = 4096 rows.
// nch(row) = min(4, rl/512 + 1).
// ---------------------------------------------------------------------------
__global__ __launch_bounds__(256)
void combine_o(const __hip_bfloat16* __restrict__ OP, const float* __restrict__ LP,
               __hip_bfloat16* __restrict__ aout)
{
    const int row = blockIdx.x;
    const int rl = row & 2047;
    const int b = row >> 11;
    const int nch = (rl >> 9) + 1;   // 1..4
    const int tid = threadIdx.x;
    const int c0 = tid * 8;
    const int h = c0 >> 7;
    const int pfx[4] = {0, 4096, 7168, 9216};

    float acc[8] = {};
    float l = 0.f;
    for (int c = 0; c < nch; c++) {
        long long rb = pfx[c] + (long long)b * (2048 - 512 * c) + (rl - 512 * c);
        l += LP[rb * 16 + h];
        u16x8 v = *reinterpret_cast<const u16x8*>(OP + rb * 2048 + c0);
        for (int j = 0; j < 8; j++)
            acc[j] += bf2f(((const unsigned short*)&v)[j]);
    }
    float inv = 1.0f / fmaxf(l, 1e-30f);
    u16x8 o;
    for (int j = 0; j < 8; j++)
        ((unsigned short*)&o)[j] = f2bf(finclamp(acc[j] * inv));
    *reinterpret_cast<u16x8*>(aout + (long long)row * 2048 + c0) = o;
}

// ---------------------------------------------------------------------------
extern "C" void kernel_launch(void* const* d_in, const int* in_sizes, int n_in,
                              void* d_out, int out_size, void* d_ws, size_t ws_size,
                              hipStream_t stream)
{
    const long long want[9] = {
        8388608, 3145728, 1536, 4718592, 1179648, 512, 1048576, 1048576, 4194304
    };
    const void* P[9] = {};
    {
        int j = 0;
        for (int i = 0; i < n_in && j < 9; i++)
            if ((long long)in_sizes[i] == want[j]) P[j++] = d_in[i];
        if (!P[8]) {
            const int map[9] = {0, 2, 3, 4, 5, 6, 7, 8, 9};
            for (int j2 = 0; j2 < 9; j2++) P[j2] = d_in[map[j2]];
        }
    }
    (void)ws_size; (void)out_size;

    char* ws = (char*)d_ws;
    int* flag = (int*)ws;
    char* A = ws + 256;

    // Region A (52.2 MB): dead after step 7; overlaid by flash partials:
    //   OP: 10240 rows x 2048 bf16 = 41,943,040 B; LP: 10240x16 fp32 = 655,360 B
    __hip_bfloat16* xc     = (__hip_bfloat16*)(A);              // 16,777,216
    __hip_bfloat16* wfused = (__hip_bfloat16*)(A + 16777216);   //  8,650,752
    __hip_bfloat16* wqbc   = (__hip_bfloat16*)(A + 25427968);   //  9,437,184
    __hip_bfloat16* cq     = (__hip_bfloat16*)(A + 34865152);   // 17,301,504 -> ends 52,166,656
    __hip_bfloat16* OP = (__hip_bfloat16*)(A);                  // 41,943,040
    float*          LP = (float*)(A + 41943040);                //    655,360

    long long off = 256 + 52166656;
    auto alloc = [&](long long bytes) {
        char* p = ws + off;
        off += ((bytes + 255) / 256) * 256;
        return p;
    };
    __hip_bfloat16* qlnwc  = (__hip_bfloat16*)alloc(3072);
    __hip_bfloat16* kvlnwc = (__hip_bfloat16*)alloc(1024);
    __hip_bfloat16* wembc  = (__hip_bfloat16*)alloc(2097152);
    __hip_bfloat16* wunec  = (__hip_bfloat16*)alloc(2097152);
    __hip_bfloat16* woc    = (__hip_bfloat16*)alloc(8388608);
    __hip_bfloat16* kvl    = (__hip_bfloat16*)alloc(4194304);
    __hip_bfloat16* kpe    = (__hip_bfloat16*)alloc(524288);
    __hip_bfloat16* wBk    = (__hip_bfloat16*)alloc(2097152);
    __hip_bfloat16* kvK    = (__hip_bfloat16*)alloc(16777216);
    __hip_bfloat16* kvVt   = (__hip_bfloat16*)alloc(16777216);
    __hip_bfloat16* qbuf   = (__hip_bfloat16*)alloc(25165824);
    __hip_bfloat16* aout   = (__hip_bfloat16*)alloc(16777216);

    // 0) detect dtype; convert all 9 inputs
    detect_fp32<<<1, 64, 0, stream>>>((const unsigned short*)P[0], flag);
    ConvDesc cd;
    cd.src[0] = P[0]; cd.dst[0] = xc;                  cd.n8[0] = 8388608 / 8;
    cd.src[1] = P[4]; cd.dst[1] = wfused;              cd.n8[1] = 1179648 / 8;
    cd.src[2] = P[1]; cd.dst[2] = wfused + 576LL*2048; cd.n8[2] = 3145728 / 8;
    cd.src[3] = P[2]; cd.dst[3] = qlnwc;               cd.n8[3] = 1536 / 8;
    cd.src[4] = P[3]; cd.dst[4] = wqbc;                cd.n8[4] = 4718592 / 8;
    cd.src[5] = P[5]; cd.dst[5] = kvlnwc;              cd.n8[5] = 512 / 8;
    cd.src[6] = P[6]; cd.dst[6] = wembc;               cd.n8[6] = 1048576 / 8;
    cd.src[7] = P[7]; cd.dst[7] = wunec;               cd.n8[7] = 1048576 / 8;
    cd.src[8] = P[8]; cd.dst[8] = woc;                 cd.n8[8] = 4194304 / 8;
    conv_all<<<dim3(512, 9), 256, 0, stream>>>(cd, flag);

    // 1) cq = x @ [wkv_a; wq_a]^T   (4096, 2112, 2048)
    gemm_bt<<<dim3(17, 32, 1), 256, 0, stream>>>(
        xc, wfused, cq, 4096, 2112, 2048, 2048, 2048, 2112, 1.0f,
        1, 1, 0, 1, 1, 0, 0, flag, 0);
    // 2) kv latent norm + k_pe rope
    kv_norm_rope<<<1024, 256, 0, stream>>>(cq, kvlnwc, kvl, kpe);
    // 3) wBk = embed^T
    transpose_embed<<<dim3(8, 16), 256, 0, stream>>>(wembc, wBk);
    // 4) K-expand: kvK = kvl[b] @ wBk[h]^T  (2048,128,512) per (b,h)
    gemm_bt<<<dim3(1, 16, 32), 256, 0, stream>>>(
        kvl, wBk, kvK, 2048, 128, 512, 512, 512, 128, 1.0f,
        16, 2, (long long)L_SEQ * KVLR, 1, 16, 128LL * KVLR,
        (long long)L_SEQ * 128, flag, 0);
    // 5) V-expand transposed: kvVt = wune[h] @ kvl[b]^T  (128,2048,512)
    gemm_bt<<<dim3(16, 1, 32), 256, 0, stream>>>(
        wunec, kvl, kvVt, 128, 2048, 512, 512, 512, 2048, 1.0f,
        1, 16, 128LL * KVLR, 16, 2, (long long)L_SEQ * KVLR,
        128LL * L_SEQ, flag, 0);
    // 6) rmsnorm(q_a) in place (cq cols 576..2111)
    rmsnorm_qa<<<4096, 256, 0, stream>>>(cq + 576, qlnwc, 2112);
    // 7) q = rmsnorm(q_a) @ wq_b^T * (SQ*SCALE*log2e)
    gemm_bt<<<dim3(24, 32, 1), 256, 0, stream>>>(
        cq + 576, wqbc, qbuf, 4096, 3072, 1536, 2112, 1536, 3072,
        0.1202245867417521f,   // (1/12) * log2(e)
        1, 1, 0, 1, 1, 0, 0, flag, 0);
    // 7b) rope q_pe in place
    rope_q<<<4096, 256, 0, stream>>>(qbuf);
    // 8) 4-way split-K flash -> bf16 partials (overlaying dead region A)
    flash_attn<<<dim3(80, 32), 256, 0, stream>>>(
        qbuf, kvK, kvVt, kpe, OP, LP);
    // 8b) combine partials -> aout (bf16)
    combine_o<<<4096, 256, 0, stream>>>(OP, LP, aout);
    // 9) out = aout @ wo^T  (fp32 out if inputs were fp32)
    gemm_bt<<<dim3(16, 32, 1), 256, 0, stream>>>(
        aout, woc, (void*)d_out, 4096, 2048, 2048, 2048, 2048, 2048, 1.0f,
        1, 1, 0, 1, 1, 0, 0, flag, 1);
}

// Round 9
// 499.650 us; speedup vs baseline: 5.3835x; 1.0622x over previous
//
#include <hip/hip_runtime.h>
#include <hip/hip_bf16.h>

// Problem constants
#define B_SZ   2
#define L_SEQ  2048
#define HIDD   2048
#define NH     16
#define QL     1536
#define KVLR   512
#define ROPE_D 64
#define NOPE_D 128
#define VD     128
#define QKD    192   // NOPE + ROPE

typedef __attribute__((ext_vector_type(8))) __bf16 bf16x8;
typedef __attribute__((ext_vector_type(4))) float  f32x4;
typedef __attribute__((ext_vector_type(8))) unsigned short u16x8;

#if __has_builtin(__builtin_amdgcn_exp2f)
#define EXP2(x) __builtin_amdgcn_exp2f(x)
#else
#define EXP2(x) exp2f(x)
#endif

__device__ __forceinline__ float bf2f(unsigned short u) {
    union { float f; unsigned int i; } x; x.i = ((unsigned int)u) << 16; return x.f;
}
__device__ __forceinline__ unsigned short f2bf(float f) {
    __hip_bfloat16 h = __float2bfloat16(f);
    return *reinterpret_cast<unsigned short*>(&h);
}
__device__ __forceinline__ float finclamp(float v) {
    return fminf(fmaxf(v, -3.3e38f), 3.3e38f);
}

// async global->LDS, 16B per lane; LDS dest = wave-uniform base + lane*16.
__device__ __forceinline__ void gld_lds16(const __hip_bfloat16* g, __hip_bfloat16* l)
{
    __builtin_amdgcn_global_load_lds(
        (const __attribute__((address_space(1))) unsigned int*)(g),
        (__attribute__((address_space(3))) unsigned int*)(l),
        16, 0, 0);
}

// ---------------------------------------------------------------------------
__global__ void detect_fp32(const unsigned short* __restrict__ x, int* __restrict__ flag)
{
    if (threadIdx.x == 0 && blockIdx.x == 0) {
        int c = 0;
        for (int i = 0; i < 128; i++) {
            unsigned e = (x[2 * i] >> 7) & 0xFF;
            if (e > 150 || (e > 0 && e < 100)) c++;
        }
        *flag = (c >= 16) ? 1 : 0;
    }
}

// ---------------------------------------------------------------------------
struct ConvDesc {
    const void* src[9];
    __hip_bfloat16* dst[9];
    long long n8[9];
};

__global__ __launch_bounds__(256)
void conv_all(ConvDesc d, const int* __restrict__ flag)
{
    const int seg = blockIdx.y;
    const void* src = d.src[seg];
    __hip_bfloat16* dst = d.dst[seg];
    const long long n8 = d.n8[seg];
    const int isf = *flag;
    long long stride = (long long)gridDim.x * 256;
    for (long long i = (long long)blockIdx.x * 256 + threadIdx.x; i < n8; i += stride) {
        u16x8 o;
        if (isf) {
            const float* s = (const float*)src + i * 8;
            float4 a = *(const float4*)s;
            float4 b = *(const float4*)(s + 4);
            o[0] = f2bf(a.x); o[1] = f2bf(a.y); o[2] = f2bf(a.z); o[3] = f2bf(a.w);
            o[4] = f2bf(b.x); o[5] = f2bf(b.y); o[6] = f2bf(b.z); o[7] = f2bf(b.w);
        } else {
            o = ((const u16x8*)src)[i];
        }
        ((u16x8*)dst)[i] = o;
    }
}

// ---------------------------------------------------------------------------
// C = scale*(A.B^T), bf16, 128x128 tile, BK=32, global_load_lds staging.
// EXACT round-4 body. Batched over grid.z. Used for cq and wo.
// ---------------------------------------------------------------------------
__global__ __launch_bounds__(256)
void gemm_bt(const __hip_bfloat16* __restrict__ A,
             const __hip_bfloat16* __restrict__ Bm,
             void* __restrict__ Cv,
             int M, int N, int K, int lda, int ldb, int ldc,
             float scale,
             int dA, int mA, long long sA,
             int dB, int mB, long long sB, long long sC,
             const int* __restrict__ flagp, int fp32out)
{
    int z = blockIdx.z;
    A  += (long long)((z / dA) % mA) * sA;
    Bm += (long long)((z / dB) % mB) * sB;
    const long long coff = (long long)z * sC;

    __shared__ __hip_bfloat16 As[128 * 32];
    __shared__ __hip_bfloat16 Bs[128 * 32];

    const int tid  = threadIdx.x;
    const int lane = tid & 63;
    const int wid  = tid >> 6;
    const int quad = lane >> 4;
    const int l15  = lane & 15;
    const int wm   = (wid >> 1) * 64;
    const int wn   = (wid & 1) * 64;

    const int m0 = blockIdx.y * 128;
    const int n0 = blockIdx.x * 128;

    const int srow = lane >> 2;
    const int scol = (lane & 3) * 8;

    f32x4 acc[4][4] = {};

    for (int k0 = 0; k0 < K; k0 += 32) {
        __syncthreads();
        for (int i = 0; i < 2; i++) {
            int rbase = wid * 32 + i * 16;
            int r = rbase + srow;
            gld_lds16(A + (long long)(m0 + r) * lda + k0 + scol, &As[rbase * 32]);
            int gn = n0 + r; if (gn >= N) gn = N - 1;
            gld_lds16(Bm + (long long)gn * ldb + k0 + scol, &Bs[rbase * 32]);
        }
        __syncthreads();

        bf16x8 af[4], bfv[4];
        for (int mt = 0; mt < 4; mt++)
            af[mt] = *reinterpret_cast<const bf16x8*>(
                &As[(wm + mt * 16 + l15) * 32 + quad * 8]);
        for (int nt = 0; nt < 4; nt++)
            bfv[nt] = *reinterpret_cast<const bf16x8*>(
                &Bs[(wn + nt * 16 + l15) * 32 + quad * 8]);
        for (int mt = 0; mt < 4; mt++)
            for (int nt = 0; nt < 4; nt++)
                acc[mt][nt] = __builtin_amdgcn_mfma_f32_16x16x32_bf16(
                    af[mt], bfv[nt], acc[mt][nt], 0, 0, 0);
    }

    const int f32o = fp32out && (*flagp);

    for (int mt = 0; mt < 4; mt++) {
        int row = m0 + wm + mt * 16 + quad * 4;
        for (int nt = 0; nt < 4; nt++) {
            int col = n0 + wn + nt * 16 + l15;
            if (col < N) {
                for (int r = 0; r < 4; r++) {
                    float val = finclamp(acc[mt][nt][r] * scale);
                    long long idx = coff + (long long)(row + r) * ldc + col;
                    if (f32o) ((float*)Cv)[idx] = val;
                    else      ((__hip_bfloat16*)Cv)[idx] = __float2bfloat16(val);
                }
            }
        }
    }
}

// ---------------------------------------------------------------------------
// gemm3: three independent GEMMs in ONE dispatch (fills >1.7 residency
// rounds vs <=0.75 each separately). Per-block uniform param select.
// ---------------------------------------------------------------------------
struct GP {
    const __hip_bfloat16* A;
    const __hip_bfloat16* B;
    __hip_bfloat16* C;
    int N, K, lda, ldb, ldc;
    float scale;
    int dA, mA; long long sA;
    int dB, mB; long long sB, sC;
    int nblk, gx, gxy;
};

__global__ __launch_bounds__(256)
void gemm3(GP g0, GP g1, GP g2)
{
    GP p; int t;
    int bid = blockIdx.x;
    if (bid < g0.nblk)               { p = g0; t = bid; }
    else if (bid < g0.nblk + g1.nblk){ p = g1; t = bid - g0.nblk; }
    else                             { p = g2; t = bid - g0.nblk - g1.nblk; }
    const int lz = t / p.gxy;
    const int rr2 = t % p.gxy;
    const int ly = rr2 / p.gx;
    const int lx = rr2 % p.gx;

    const __hip_bfloat16* A  = p.A + (long long)((lz / p.dA) % p.mA) * p.sA;
    const __hip_bfloat16* Bm = p.B + (long long)((lz / p.dB) % p.mB) * p.sB;
    const long long coff = (long long)lz * p.sC;
    const int N = p.N, K = p.K, lda = p.lda, ldb = p.ldb, ldc = p.ldc;

    __shared__ __hip_bfloat16 As[128 * 32];
    __shared__ __hip_bfloat16 Bs[128 * 32];

    const int tid  = threadIdx.x;
    const int lane = tid & 63;
    const int wid  = tid >> 6;
    const int quad = lane >> 4;
    const int l15  = lane & 15;
    const int wm   = (wid >> 1) * 64;
    const int wn   = (wid & 1) * 64;

    const int m0 = ly * 128;
    const int n0 = lx * 128;

    const int srow = lane >> 2;
    const int scol = (lane & 3) * 8;

    f32x4 acc[4][4] = {};

    for (int k0 = 0; k0 < K; k0 += 32) {
        __syncthreads();
        for (int i = 0; i < 2; i++) {
            int rbase = wid * 32 + i * 16;
            int r = rbase + srow;
            gld_lds16(A + (long long)(m0 + r) * lda + k0 + scol, &As[rbase * 32]);
            int gn = n0 + r; if (gn >= N) gn = N - 1;
            gld_lds16(Bm + (long long)gn * ldb + k0 + scol, &Bs[rbase * 32]);
        }
        __syncthreads();

        bf16x8 af[4], bfv[4];
        for (int mt = 0; mt < 4; mt++)
            af[mt] = *reinterpret_cast<const bf16x8*>(
                &As[(wm + mt * 16 + l15) * 32 + quad * 8]);
        for (int nt = 0; nt < 4; nt++)
            bfv[nt] = *reinterpret_cast<const bf16x8*>(
                &Bs[(wn + nt * 16 + l15) * 32 + quad * 8]);
        for (int mt = 0; mt < 4; mt++)
            for (int nt = 0; nt < 4; nt++)
                acc[mt][nt] = __builtin_amdgcn_mfma_f32_16x16x32_bf16(
                    af[mt], bfv[nt], acc[mt][nt], 0, 0, 0);
    }

    __hip_bfloat16* C = p.C;
    const float scale = p.scale;
    for (int mt = 0; mt < 4; mt++) {
        int row = m0 + wm + mt * 16 + quad * 4;
        for (int nt = 0; nt < 4; nt++) {
            int col = n0 + wn + nt * 16 + l15;
            if (col < N) {
                for (int r = 0; r < 4; r++) {
                    float val = finclamp(acc[mt][nt][r] * scale);
                    C[coff + (long long)(row + r) * ldc + col] = __float2bfloat16(val);
                }
            }
        }
    }
}

// ---------------------------------------------------------------------------
// prep3: fused {kv_norm_rope (1024 blk) | rmsnorm_qa (4096 blk) |
// transpose_embed (128 blk)} -- all independent, all depend only on cq/conv.
// ---------------------------------------------------------------------------
__global__ __launch_bounds__(256)
void prep3(const __hip_bfloat16* __restrict__ CQ,    // (4096, 2112)
           __hip_bfloat16* __restrict__ CQm,          // mutable alias
           const __hip_bfloat16* __restrict__ KVW,
           const __hip_bfloat16* __restrict__ QW,
           const __hip_bfloat16* __restrict__ WE,
           __hip_bfloat16* __restrict__ KVLAT,
           __hip_bfloat16* __restrict__ KPE,
           __hip_bfloat16* __restrict__ WB)
{
    __shared__ __hip_bfloat16 tls[64 * 136];   // transpose tile; rmsnorm scratch
    const int blk = blockIdx.x;
    const int tid = threadIdx.x;

    if (blk < 1024) {
        // ---- kv_norm_rope: 4 rows per block ----
        int row = blk * 4 + (tid >> 6);
        int l = row & (L_SEQ - 1);
        int t = tid & 63;
        const __hip_bfloat16* cr = CQ + (long long)row * 2112;
        float v[8]; float ss = 0.f;
        u16x8 raw = *reinterpret_cast<const u16x8*>(cr + t * 8);
        for (int j = 0; j < 8; j++) {
            v[j] = bf2f(((const unsigned short*)&raw)[j]);
            ss += v[j] * v[j];
        }
        for (int m = 1; m < 64; m <<= 1) ss += __shfl_xor(ss, m, 64);
        float inv = rsqrtf(ss / (float)KVLR + 1e-5f) * 2.0f;  // SKV = 2
        u16x8 wr = *reinterpret_cast<const u16x8*>(KVW + t * 8);
        u16x8 o;
        for (int j = 0; j < 8; j++)
            ((unsigned short*)&o)[j] =
                f2bf(finclamp(v[j] * inv * bf2f(((const unsigned short*)&wr)[j])));
        *reinterpret_cast<u16x8*>(KVLAT + (long long)row * KVLR + t * 8) = o;
        if (t < 32) {
            float freq = exp2f(-(float)t * (13.287712379549449f / 32.0f));
            float th = (float)l * freq;
            float s = __sinf(th), c = __cosf(th);
            float x1 = __bfloat162float(cr[512 + 2 * t]);
            float x2 = __bfloat162float(cr[512 + 2 * t + 1]);
            __hip_bfloat16* kp = KPE + (long long)row * 64;
            kp[2 * t]     = __float2bfloat16(finclamp(x1 * c - x2 * s));
            kp[2 * t + 1] = __float2bfloat16(finclamp(x1 * s + x2 * c));
        }
    } else if (blk < 5120) {
        // ---- rmsnorm over cq cols 576..2111, row = blk-1024 ----
        int row = blk - 1024;
        __hip_bfloat16* xr = CQm + (long long)row * 2112 + 576;
        bool act = tid < (QL / 8);
        float v[8]; float ss = 0.f;
        if (act) {
            u16x8 raw = *reinterpret_cast<const u16x8*>(xr + tid * 8);
            for (int j = 0; j < 8; j++) {
                v[j] = bf2f(((const unsigned short*)&raw)[j]);
                ss += v[j] * v[j];
            }
        }
        for (int m = 1; m < 64; m <<= 1) ss += __shfl_xor(ss, m, 64);
        float* ws4 = (float*)tls;
        if ((tid & 63) == 0) ws4[tid >> 6] = ss;
        __syncthreads();
        float tot = ws4[0] + ws4[1] + ws4[2] + ws4[3];
        float inv = rsqrtf(tot / (float)QL + 1e-5f);
        if (act) {
            u16x8 wr = *reinterpret_cast<const u16x8*>(QW + tid * 8);
            u16x8 o;
            for (int j = 0; j < 8; j++)
                ((unsigned short*)&o)[j] =
                    f2bf(finclamp(v[j] * inv * bf2f(((const unsigned short*)&wr)[j])));
            *reinterpret_cast<u16x8*>(xr + tid * 8) = o;
        }
    } else {
        // ---- transpose_embed: t = blk-5120; h = t>>3; k0 = (t&7)*64 ----
        int t = blk - 5120;
        int h = t >> 3;
        int k0 = (t & 7) * 64;
        for (int it = 0; it < 4; it++) {
            int s = tid + it * 256;
            int k = s >> 4, cg = (s & 15) * 8;
            u16x8 v = *reinterpret_cast<const u16x8*>(
                WE + ((long long)h * KVLR + k0 + k) * NOPE_D + cg);
            *reinterpret_cast<u16x8*>(&tls[k * 136 + cg]) = v;
        }
        __syncthreads();
        for (int it = 0; it < 4; it++) {
            int s = tid + it * 256;
            int n = s >> 3, kg = (s & 7) * 8;
            u16x8 o;
            for (int j = 0; j < 8; j++)
                ((unsigned short*)&o)[j] =
                    *reinterpret_cast<unsigned short*>(&tls[(kg + j) * 136 + n]);
            *reinterpret_cast<u16x8*>(WB + ((long long)h * 128 + n) * KVLR + k0 + kg) = o;
        }
    }
}

// ---------------------------------------------------------------------------
// In-place traditional RoPE on q_pe cols h*192+128..191 of qbuf (B*L, 3072).
// ---------------------------------------------------------------------------
__global__ __launch_bounds__(256)
void rope_q(__hip_bfloat16* __restrict__ Q)
{
    int row = blockIdx.x;
    int l = row & (L_SEQ - 1);
    int tid = threadIdx.x;
    for (int p = tid; p < NH * 32; p += 256) {
        int h = p >> 5, i = p & 31;
        __hip_bfloat16* base = Q + (long long)row * (NH * QKD) + h * QKD + NOPE_D + 2 * i;
        float freq = exp2f(-(float)i * (13.287712379549449f / 32.0f));
        float th = (float)l * freq;
        float s = __sinf(th), c = __cosf(th);
        float x1 = __bfloat162float(base[0]);
        float x2 = __bfloat162float(base[1]);
        base[0] = __float2bfloat16(finclamp(x1 * c - x2 * s));
        base[1] = __float2bfloat16(finclamp(x1 * s + x2 * c));
    }
}

// ---------------------------------------------------------------------------
// 4-way split-K flash attention (unchanged from round 8).
// ---------------------------------------------------------------------------
__global__ __launch_bounds__(256)
void flash_attn(const __hip_bfloat16* __restrict__ Q,
                const __hip_bfloat16* __restrict__ Kb,
                const __hip_bfloat16* __restrict__ Vt,
                const __hip_bfloat16* __restrict__ KPE,
                __hip_bfloat16* __restrict__ OP,
                float* __restrict__ LP)
{
    const int u = blockIdx.x;
    int c, qt;
    if (u < 32)      { c = 0; qt = 31 - u; }
    else if (u < 56) { c = 1; qt = 31 - (u - 32); }
    else if (u < 72) { c = 2; qt = 31 - (u - 56); }
    else             { c = 3; qt = 31 - (u - 72); }
    const int q0 = qt * 64;
    const int t0 = c * 8;
    const int t1 = (qt + 1 < t0 + 8) ? (qt + 1) : (t0 + 8);

    const int bh = blockIdx.y;
    const int b = bh >> 4;
    const int h = bh & 15;

    __shared__ __hip_bfloat16 Ks[64 * 200];
    __shared__ __hip_bfloat16 Vs[128 * 72];
    __shared__ __hip_bfloat16 Ps[4][16 * 72];

    const int tid  = threadIdx.x;
    const int lane = tid & 63;
    const int w    = tid >> 6;
    const int quad = lane >> 4;
    const int l15  = lane & 15;

    const __hip_bfloat16* Kbh  = Kb + (long long)bh * L_SEQ * 128;
    const __hip_bfloat16* Vth  = Vt + (long long)bh * 128 * L_SEQ;
    const __hip_bfloat16* KPEb = KPE + (long long)b * L_SEQ * 64;

    bf16x8 qf[6];
    {
        long long qoff = (long long)(b * L_SEQ + q0 + w * 16 + l15) * (NH * QKD) + h * QKD;
        for (int kk = 0; kk < 6; kk++)
            qf[kk] = *reinterpret_cast<const bf16x8*>(Q + qoff + kk * 32 + quad * 8);
    }

    f32x4 o_acc[8] = {};
    float l_run[4] = {0.f, 0.f, 0.f, 0.f};

    for (int kt = t0; kt < t1; kt++) {
        const int kk0 = kt * 64;
        const bool partial = (kt == qt);
        __syncthreads();
        for (int it = 0; it < 6; it++) {
            int s = tid + it * 256;
            int r = s / 24, cg = s % 24;
            u16x8 v;
            if (cg < 16)
                v = *reinterpret_cast<const u16x8*>(
                    Kbh + (long long)(kk0 + r) * 128 + cg * 8);
            else
                v = *reinterpret_cast<const u16x8*>(
                    KPEb + (long long)(kk0 + r) * 64 + (cg - 16) * 8);
            *reinterpret_cast<u16x8*>(&Ks[r * 200 + cg * 8]) = v;
        }
        for (int it = 0; it < 4; it++) {
            int s = tid + it * 256;
            int vd = s >> 3, kg = (s & 7) * 8;
            u16x8 v = *reinterpret_cast<const u16x8*>(
                Vth + (long long)vd * L_SEQ + kk0 + kg);
            *reinterpret_cast<u16x8*>(&Vs[vd * 72 + kg]) = v;
        }
        __syncthreads();

        f32x4 sfr[4];
        for (int nt = 0; nt < 4; nt++) {
            f32x4 sacc = {};
            for (int kk = 0; kk < 6; kk++) {
                bf16x8 kf = *reinterpret_cast<const bf16x8*>(
                    &Ks[(nt * 16 + l15) * 200 + kk * 32 + quad * 8]);
                sacc = __builtin_amdgcn_mfma_f32_16x16x32_bf16(qf[kk], kf, sacc, 0, 0, 0);
            }
            sfr[nt] = sacc;
        }

        const int qrow_base = q0 + w * 16 + quad * 4;
        float rs[4] = {0.f, 0.f, 0.f, 0.f};
        if (partial) {
            for (int nt = 0; nt < 4; nt++) {
                int key = kk0 + nt * 16 + l15;
                for (int r = 0; r < 4; r++) {
                    float p = (key > qrow_base + r) ? 0.f : EXP2(sfr[nt][r]);
                    sfr[nt][r] = p;
                    rs[r] += p;
                }
            }
        } else {
            for (int nt = 0; nt < 4; nt++)
                for (int r = 0; r < 4; r++) {
                    float p = EXP2(sfr[nt][r]);
                    sfr[nt][r] = p;
                    rs[r] += p;
                }
        }

        for (int nt = 0; nt < 4; nt++)
            for (int r = 0; r < 4; r++)
                Ps[w][(quad * 4 + r) * 72 + nt * 16 + l15] =
                    __float2bfloat16(sfr[nt][r]);

        for (int r = 0; r < 4; r++) {
            float t = rs[r];
            for (int m = 1; m < 16; m <<= 1) t += __shfl_xor(t, m, 16);
            l_run[r] += t;
        }

        for (int ks = 0; ks < 2; ks++) {
            bf16x8 pf = *reinterpret_cast<const bf16x8*>(
                &Ps[w][l15 * 72 + ks * 32 + quad * 8]);
            for (int vt = 0; vt < 8; vt++) {
                bf16x8 vf = *reinterpret_cast<const bf16x8*>(
                    &Vs[(vt * 16 + l15) * 72 + ks * 32 + quad * 8]);
                o_acc[vt] = __builtin_amdgcn_mfma_f32_16x16x32_bf16(pf, vf, o_acc[vt], 0, 0, 0);
            }
        }
    }

    const int pfx[4] = {0, 4096, 7168, 9216};
    const int orow = q0 + w * 16 + quad * 4;
    const long long rb0 = pfx[c] + (long long)b * (2048 - 512 * c) + (orow - 512 * c);
    for (int r = 0; r < 4; r++) {
        __hip_bfloat16* op = OP + (rb0 + r) * 2048 + h * 128;
        for (int vt = 0; vt < 8; vt++)
            op[vt * 16 + l15] = __float2bfloat16(finclamp(o_acc[vt][r]));
        if (l15 == 0) LP[(rb0 + r) * 16 + h] = l_run[r];
    }
}

// ---------------------------------------------------------------------------
__global__ __launch_bounds__(256)
void combine_o(const __hip_bfloat16* __restrict__ OP, const float* __restrict__ LP,
               __hip_bfloat16* __restrict__ aout)
{
    const int row = blockIdx.x;
    const int rl = row & 2047;
    const int b = row >> 11;
    const int nch = (rl >> 9) + 1;   // 1..4
    const int tid = threadIdx.x;
    const int c0 = tid * 8;
    const int h = c0 >> 7;
    const int pfx[4] = {0, 4096, 7168, 9216};

    float acc[8] = {};
    float l = 0.f;
    for (int c = 0; c < nch; c++) {
        long long rb = pfx[c] + (long long)b * (2048 - 512 * c) + (rl - 512 * c);
        l += LP[rb * 16 + h];
        u16x8 v = *reinterpret_cast<const u16x8*>(OP + rb * 2048 + c0);
        for (int j = 0; j < 8; j++)
            acc[j] += bf2f(((const unsigned short*)&v)[j]);
    }
    float inv = 1.0f / fmaxf(l, 1e-30f);
    u16x8 o;
    for (int j = 0; j < 8; j++)
        ((unsigned short*)&o)[j] = f2bf(finclamp(acc[j] * inv));
    *reinterpret_cast<u16x8*>(aout + (long long)row * 2048 + c0) = o;
}

// ---------------------------------------------------------------------------
extern "C" void kernel_launch(void* const* d_in, const int* in_sizes, int n_in,
                              void* d_out, int out_size, void* d_ws, size_t ws_size,
                              hipStream_t stream)
{
    const long long want[9] = {
        8388608, 3145728, 1536, 4718592, 1179648, 512, 1048576, 1048576, 4194304
    };
    const void* P[9] = {};
    {
        int j = 0;
        for (int i = 0; i < n_in && j < 9; i++)
            if ((long long)in_sizes[i] == want[j]) P[j++] = d_in[i];
        if (!P[8]) {
            const int map[9] = {0, 2, 3, 4, 5, 6, 7, 8, 9};
            for (int j2 = 0; j2 < 9; j2++) P[j2] = d_in[map[j2]];
        }
    }
    (void)ws_size; (void)out_size;

    char* ws = (char*)d_ws;
    int* flag = (int*)ws;
    char* A = ws + 256;

    // Region A (52.2 MB): dead after gemm3; overlaid by flash partials.
    __hip_bfloat16* xc     = (__hip_bfloat16*)(A);              // 16,777,216
    __hip_bfloat16* wfused = (__hip_bfloat16*)(A + 16777216);   //  8,650,752
    __hip_bfloat16* wqbc   = (__hip_bfloat16*)(A + 25427968);   //  9,437,184
    __hip_bfloat16* cq     = (__hip_bfloat16*)(A + 34865152);   // 17,301,504 -> ends 52,166,656
    __hip_bfloat16* OP = (__hip_bfloat16*)(A);                  // 41,943,040
    float*          LP = (float*)(A + 41943040);                //    655,360

    long long off = 256 + 52166656;
    auto alloc = [&](long long bytes) {
        char* p = ws + off;
        off += ((bytes + 255) / 256) * 256;
        return p;
    };
    __hip_bfloat16* qlnwc  = (__hip_bfloat16*)alloc(3072);
    __hip_bfloat16* kvlnwc = (__hip_bfloat16*)alloc(1024);
    __hip_bfloat16* wembc  = (__hip_bfloat16*)alloc(2097152);
    __hip_bfloat16* wunec  = (__hip_bfloat16*)alloc(2097152);
    __hip_bfloat16* woc    = (__hip_bfloat16*)alloc(8388608);
    __hip_bfloat16* kvl    = (__hip_bfloat16*)alloc(4194304);
    __hip_bfloat16* kpe    = (__hip_bfloat16*)alloc(524288);
    __hip_bfloat16* wBk    = (__hip_bfloat16*)alloc(2097152);
    __hip_bfloat16* kvK    = (__hip_bfloat16*)alloc(16777216);
    __hip_bfloat16* kvVt   = (__hip_bfloat16*)alloc(16777216);
    __hip_bfloat16* qbuf   = (__hip_bfloat16*)alloc(25165824);
    __hip_bfloat16* aout   = (__hip_bfloat16*)alloc(16777216);

    // 0) detect dtype; convert all 9 inputs
    detect_fp32<<<1, 64, 0, stream>>>((const unsigned short*)P[0], flag);
    ConvDesc cd;
    cd.src[0] = P[0]; cd.dst[0] = xc;                  cd.n8[0] = 8388608 / 8;
    cd.src[1] = P[4]; cd.dst[1] = wfused;              cd.n8[1] = 1179648 / 8;
    cd.src[2] = P[1]; cd.dst[2] = wfused + 576LL*2048; cd.n8[2] = 3145728 / 8;
    cd.src[3] = P[2]; cd.dst[3] = qlnwc;               cd.n8[3] = 1536 / 8;
    cd.src[4] = P[3]; cd.dst[4] = wqbc;                cd.n8[4] = 4718592 / 8;
    cd.src[5] = P[5]; cd.dst[5] = kvlnwc;              cd.n8[5] = 512 / 8;
    cd.src[6] = P[6]; cd.dst[6] = wembc;               cd.n8[6] = 1048576 / 8;
    cd.src[7] = P[7]; cd.dst[7] = wunec;               cd.n8[7] = 1048576 / 8;
    cd.src[8] = P[8]; cd.dst[8] = woc;                 cd.n8[8] = 4194304 / 8;
    conv_all<<<dim3(512, 9), 256, 0, stream>>>(cd, flag);

    // 1) cq = x @ [wkv_a; wq_a]^T   (4096, 2112, 2048)
    gemm_bt<<<dim3(17, 32, 1), 256, 0, stream>>>(
        xc, wfused, cq, 4096, 2112, 2048, 2048, 2048, 2112, 1.0f,
        1, 1, 0, 1, 1, 0, 0, flag, 0);
    // 2) prep3: kv_norm_rope + rmsnorm(q_a) + transpose_embed, one dispatch
    prep3<<<5248, 256, 0, stream>>>(cq, cq, kvlnwc, qlnwc, wembc,
                                    kvl, kpe, wBk);
    // 3) gemm3: q_b (768 blk, K=1536, first) + kvK (512) + kvVt (512)
    {
        GP g0, g1, g2;
        // q_b: C=qbuf (4096,3072), A=cq+576 lda=2112, B=wqbc
        g0.A = cq + 576; g0.B = wqbc; g0.C = qbuf;
        g0.N = 3072; g0.K = 1536; g0.lda = 2112; g0.ldb = 1536; g0.ldc = 3072;
        g0.scale = 0.1202245867417521f;   // (1/12) * log2(e)
        g0.dA = 1; g0.mA = 1; g0.sA = 0;
        g0.dB = 1; g0.mB = 1; g0.sB = 0; g0.sC = 0;
        g0.nblk = 768; g0.gx = 24; g0.gxy = 768;
        // kvK: per (b,h): kvl[b] @ wBk[h]^T -> (2048,128)
        g1.A = kvl; g1.B = wBk; g1.C = kvK;
        g1.N = 128; g1.K = 512; g1.lda = 512; g1.ldb = 512; g1.ldc = 128;
        g1.scale = 1.0f;
        g1.dA = 16; g1.mA = 2; g1.sA = (long long)L_SEQ * KVLR;
        g1.dB = 1; g1.mB = 16; g1.sB = 128LL * KVLR; g1.sC = (long long)L_SEQ * 128;
        g1.nblk = 512; g1.gx = 1; g1.gxy = 16;
        // kvVt: per (b,h): wune[h] @ kvl[b]^T -> (128,2048)
        g2.A = wunec; g2.B = kvl; g2.C = kvVt;
        g2.N = 2048; g2.K = 512; g2.lda = 512; g2.ldb = 512; g2.ldc = 2048;
        g2.scale = 1.0f;
        g2.dA = 1; g2.mA = 16; g2.sA = 128LL * KVLR;
        g2.dB = 16; g2.mB = 2; g2.sB = (long long)L_SEQ * KVLR; g2.sC = 128LL * L_SEQ;
        g2.nblk = 512; g2.gx = 16; g2.gxy = 16;
        gemm3<<<1792, 256, 0, stream>>>(g0, g1, g2);
    }
    // 4) rope q_pe in place
    rope_q<<<4096, 256, 0, stream>>>(qbuf);
    // 5) 4-way split-K flash -> bf16 partials (overlaying dead region A)
    flash_attn<<<dim3(80, 32), 256, 0, stream>>>(
        qbuf, kvK, kvVt, kpe, OP, LP);
    // 5b) combine partials -> aout (bf16)
    combine_o<<<4096, 256, 0, stream>>>(OP, LP, aout);
    // 6) out = aout @ wo^T  (fp32 out if inputs were fp32)
    gemm_bt<<<dim3(16, 32, 1), 256, 0, stream>>>(
        aout, woc, (void*)d_out, 4096, 2048, 2048, 2048, 2048, 2048, 1.0f,
        1, 1, 0, 1, 1, 0, 0, flag, 1);
}